// Round 14
// baseline (402.827 us; speedup 1.0000x reference)
//
#include <hip/hip_runtime.h>
#include <math.h>

#define B_   4
#define NQ_  1024
#define NK_  1024
#define D_   1024
#define H_   16
#define DH_  64
#define DFF_ 4096
#define SCALE_ (1.0f/32.0f)   // 1/sqrt(D)
#define LN_EPS_ 1e-5f

typedef __attribute__((ext_vector_type(8))) short bf16x8_t;  // 8 bf16 = 4 VGPR
typedef __attribute__((ext_vector_type(4))) float f32x4_t;

__device__ __forceinline__ ushort f2bf_rne(float x) {
    unsigned u = __float_as_uint(x);
    unsigned r = (u + 0x7FFFu + ((u >> 16) & 1u)) >> 16;
    return (ushort)r;
}
__device__ __forceinline__ float bf2f(ushort h) {
    return __uint_as_float(((unsigned)h) << 16);
}

// async global->LDS, 16B per lane. LDS dest = wave-uniform base + lane*16.
__device__ __forceinline__ void gl_lds16(const ushort* g, ushort* l) {
    __builtin_amdgcn_global_load_lds(
        (const __attribute__((address_space(1))) unsigned int*)g,
        (__attribute__((address_space(3))) unsigned int*)l, 16, 0, 0);
}

// ---------------------------------------------------------------------------
// fp32 -> (hi,lo) bf16 planes; fused 2-tensor variant (z picks tensor).
// ---------------------------------------------------------------------------
struct Rows2 { const float* src[2]; ushort* hi[2]; ushort* lo[2]; };

__global__ __launch_bounds__(256) void split_rows2(Rows2 a, int n4)
{
    int i = blockIdx.x * 256 + threadIdx.x;
    if (i >= n4) return;
    const int z = blockIdx.z;
    float4 v = ((const float4*)a.src[z])[i];
    ushort4 h, l;
    h.x = f2bf_rne(v.x); l.x = f2bf_rne(v.x - bf2f(h.x));
    h.y = f2bf_rne(v.y); l.y = f2bf_rne(v.y - bf2f(h.y));
    h.z = f2bf_rne(v.z); l.z = f2bf_rne(v.z - bf2f(h.z));
    h.w = f2bf_rne(v.w); l.w = f2bf_rne(v.w - bf2f(h.w));
    ((ushort4*)a.hi[z])[i] = h;
    ((ushort4*)a.lo[z])[i] = l;
}

// ---------------------------------------------------------------------------
// Weight split + transpose: W[K][N] fp32 -> planes Wt[N][K] bf16.
// Single and fused-4 (z picks matrix; all D x D) variants.
// ---------------------------------------------------------------------------
__device__ __forceinline__ void split_tr_body(const float* __restrict__ Wsrc,
        ushort* __restrict__ th, ushort* __restrict__ tl, int K, int N)
{
    __shared__ float tile[32][33];
    const int nb = blockIdx.x * 32, kb = blockIdx.y * 32;
    const int t = threadIdx.x;
    {
        int r = t >> 3, c4 = (t & 7) * 4;
        float4 v = *(const float4*)&Wsrc[(size_t)(kb + r) * N + nb + c4];
        tile[r][c4 + 0] = v.x; tile[r][c4 + 1] = v.y;
        tile[r][c4 + 2] = v.z; tile[r][c4 + 3] = v.w;
    }
    __syncthreads();
    {
        int n = t >> 3, k4 = (t & 7) * 4;
        float a0 = tile[k4 + 0][n], a1 = tile[k4 + 1][n];
        float a2 = tile[k4 + 2][n], a3 = tile[k4 + 3][n];
        ushort4 h, l;
        h.x = f2bf_rne(a0); l.x = f2bf_rne(a0 - bf2f(h.x));
        h.y = f2bf_rne(a1); l.y = f2bf_rne(a1 - bf2f(h.y));
        h.z = f2bf_rne(a2); l.z = f2bf_rne(a2 - bf2f(h.z));
        h.w = f2bf_rne(a3); l.w = f2bf_rne(a3 - bf2f(h.w));
        size_t o = (size_t)(nb + n) * K + kb + k4;
        *(ushort4*)&th[o] = h;
        *(ushort4*)&tl[o] = l;
    }
}

__global__ __launch_bounds__(256) void split_tr(const float* __restrict__ Wsrc,
        ushort* __restrict__ th, ushort* __restrict__ tl, int K, int N)
{
    split_tr_body(Wsrc, th, tl, K, N);
}

struct Tr4 { const float* w[4]; ushort* th[4]; ushort* tl[4]; };

__global__ __launch_bounds__(256) void split_tr4(Tr4 a)
{
    const int z = blockIdx.z;
    split_tr_body(a.w[z], a.th[z], a.tl[z], D_, D_);
}

// bijective XCD-chunked swizzle (nwg % 8 == 0 for all our grids)
__device__ __forceinline__ void swz_block(int& brow, int& bcol, int tile) {
    const int nx  = gridDim.x;
    const int lin = blockIdx.y * nx + blockIdx.x;
    const int cpx = (nx * gridDim.y) >> 3;
    const int swz = (lin & 7) * cpx + (lin >> 3);
    brow = (swz / nx) * tile;
    bcol = (swz % nx) * tile;
}

// ---------------------------------------------------------------------------
// MFMA GEMM body (r10-validated counted-vmcnt fine-phase pipeline). 128^2.
// ---------------------------------------------------------------------------
template<bool RELU, int OMODE>
__device__ __forceinline__ void gemm_body(
        const ushort* __restrict__ Ah, const ushort* __restrict__ Al,
        const ushort* __restrict__ Bh, const ushort* __restrict__ Bl,
        const float* __restrict__ bias,
        float* __restrict__ C, ushort* __restrict__ Ch, ushort* __restrict__ Cl,
        int M, int N, int Kd, int Klen, int brow, int bcol)
{
    __shared__ __align__(16) ushort S[2][4][128 * 32];   // 64KB dbuf

    const int t    = threadIdx.x;
    const int lane = t & 63;
    const int w    = t >> 6;
    const int wr   = (w >> 1) * 64;
    const int wc   = (w & 1) * 64;
    const int fr   = lane & 15;
    const int g    = lane >> 4;
    const int sS   = ((g ^ ((fr >> 1) & 3)) << 3);
    const int cl   = lane & 15;
    const int rq   = (lane >> 4) * 4;

    float bpre[4];
    #pragma unroll
    for (int j = 0; j < 4; ++j)
        bpre[j] = bias ? bias[bcol + wc + j * 16 + cl] : 0.f;

    f32x4_t acc[4][4];
    #pragma unroll
    for (int i = 0; i < 4; ++i)
        #pragma unroll
        for (int j = 0; j < 4; ++j)
            acc[i][j] = (f32x4_t){0.f, 0.f, 0.f, 0.f};

    const int lrow  = lane >> 2;
    const int lslot = ((lane & 3) ^ ((lane >> 3) & 3)) << 3;
    const int c0    = w * 2;

    auto issue2 = [&](const ushort* gpp, int rb, int pl, int buf, int k0) {
        #pragma unroll
        for (int ii = 0; ii < 2; ++ii) {
            int c = c0 + ii;
            gl_lds16(gpp + (size_t)(rb + c * 16 + lrow) * Kd + k0 + lslot,
                     &S[buf][pl][c * 512]);
        }
    };

    bf16x8_t ahf[4], bhf[4], blf[4], alf[4];

    issue2(Ah, brow, 0, 0, 0);
    issue2(Bh, bcol, 2, 0, 0);
    issue2(Bl, bcol, 3, 0, 0);
    issue2(Al, brow, 1, 0, 0);
    asm volatile("s_waitcnt vmcnt(4)" ::: "memory");
    __builtin_amdgcn_s_barrier();

    const int NT = Klen >> 5;
    for (int tt = 0; tt < NT; ++tt) {
        const int cur = tt & 1, nxt = cur ^ 1;
        const int kn  = (tt + 1) << 5;
        const bool more = (tt + 1 < NT);

        // phase 0: hh
        #pragma unroll
        for (int i = 0; i < 4; ++i)
            ahf[i] = *(const bf16x8_t*)&S[cur][0][(wr + i * 16 + fr) * 32 + sS];
        #pragma unroll
        for (int j = 0; j < 4; ++j)
            bhf[j] = *(const bf16x8_t*)&S[cur][2][(wc + j * 16 + fr) * 32 + sS];
        if (more) {
            issue2(Ah, brow, 0, nxt, kn);
            issue2(Bh, bcol, 2, nxt, kn);
            asm volatile("s_waitcnt vmcnt(6)" ::: "memory");
        } else {
            asm volatile("s_waitcnt vmcnt(2)" ::: "memory");
        }
        __builtin_amdgcn_s_barrier();
        asm volatile("s_waitcnt lgkmcnt(0)" ::: "memory");
        __builtin_amdgcn_sched_barrier(0);
        __builtin_amdgcn_s_setprio(1);
        #pragma unroll
        for (int i = 0; i < 4; ++i)
            #pragma unroll
            for (int j = 0; j < 4; ++j)
                acc[i][j] = __builtin_amdgcn_mfma_f32_16x16x32_bf16(ahf[i], bhf[j], acc[i][j], 0, 0, 0);
        __builtin_amdgcn_s_setprio(0);
        __builtin_amdgcn_s_barrier();

        // phase 1: hl
        #pragma unroll
        for (int j = 0; j < 4; ++j)
            blf[j] = *(const bf16x8_t*)&S[cur][3][(wc + j * 16 + fr) * 32 + sS];
        if (more) {
            issue2(Bl, bcol, 3, nxt, kn);
            asm volatile("s_waitcnt vmcnt(6)" ::: "memory");
        } else {
            asm volatile("s_waitcnt vmcnt(0)" ::: "memory");
        }
        __builtin_amdgcn_s_barrier();
        asm volatile("s_waitcnt lgkmcnt(0)" ::: "memory");
        __builtin_amdgcn_sched_barrier(0);
        __builtin_amdgcn_s_setprio(1);
        #pragma unroll
        for (int i = 0; i < 4; ++i)
            #pragma unroll
            for (int j = 0; j < 4; ++j)
                acc[i][j] = __builtin_amdgcn_mfma_f32_16x16x32_bf16(ahf[i], blf[j], acc[i][j], 0, 0, 0);
        __builtin_amdgcn_s_setprio(0);
        __builtin_amdgcn_s_barrier();

        // phase 2: lh
        #pragma unroll
        for (int i = 0; i < 4; ++i)
            alf[i] = *(const bf16x8_t*)&S[cur][1][(wr + i * 16 + fr) * 32 + sS];
        if (more) {
            issue2(Al, brow, 1, nxt, kn);
            asm volatile("s_waitcnt vmcnt(4)" ::: "memory");
        }
        __builtin_amdgcn_s_barrier();
        asm volatile("s_waitcnt lgkmcnt(0)" ::: "memory");
        __builtin_amdgcn_sched_barrier(0);
        __builtin_amdgcn_s_setprio(1);
        #pragma unroll
        for (int i = 0; i < 4; ++i)
            #pragma unroll
            for (int j = 0; j < 4; ++j)
                acc[i][j] = __builtin_amdgcn_mfma_f32_16x16x32_bf16(alf[i], bhf[j], acc[i][j], 0, 0, 0);
        __builtin_amdgcn_s_setprio(0);
        __builtin_amdgcn_s_barrier();
    }

    if (OMODE == 0) {
        #pragma unroll
        for (int j = 0; j < 4; ++j) {
            int col = bcol + wc + j * 16 + cl;
            #pragma unroll
            for (int i = 0; i < 4; ++i)
                #pragma unroll
                for (int r = 0; r < 4; ++r) {
                    int row = brow + wr + i * 16 + rq + r;
                    float v = acc[i][j][r] + bpre[j];
                    if (RELU) v = fmaxf(v, 0.f);
                    C[(size_t)row * N + col] = v;
                }
        }
    } else {
        float* E = (float*)&S[0][0][0] + w * 4096;   // 16KB per wave
        #pragma unroll
        for (int j = 0; j < 4; ++j) {
            #pragma unroll
            for (int i = 0; i < 4; ++i)
                #pragma unroll
                for (int r = 0; r < 4; ++r) {
                    float v = acc[i][j][r] + bpre[j];
                    if (RELU) v = fmaxf(v, 0.f);
                    E[(i * 16 + rq + r) * 64 + j * 16 + cl] = v;
                }
        }
        __syncthreads();
        const int rr8 = lane >> 3;
        const int c8  = (lane & 7) * 8;
        #pragma unroll
        for (int p = 0; p < 8; ++p) {
            int rl = p * 8 + rr8;
            float4 va = *(float4*)&E[rl * 64 + c8];
            float4 vb = *(float4*)&E[rl * 64 + c8 + 4];
            float v[8] = {va.x, va.y, va.z, va.w, vb.x, vb.y, vb.z, vb.w};
            bf16x8_t hv, lv;
            #pragma unroll
            for (int q = 0; q < 8; ++q) {
                ushort hh = f2bf_rne(v[q]);
                hv[q] = (short)hh;
                lv[q] = (short)f2bf_rne(v[q] - bf2f(hh));
            }
            size_t o = (size_t)(brow + wr + rl) * N + (bcol + wc + c8);
            *(bf16x8_t*)&Ch[o] = hv;
            if (OMODE == 1) *(bf16x8_t*)&Cl[o] = lv;
        }
    }
}

// q/k/v projections fused into one dispatch (grid.z = 3 -> 768 blocks)
struct QkvArgs {
    const ushort* Ah[3]; const ushort* Al[3];
    const ushort* Bh[3]; const ushort* Bl[3];
    const float*  bias[3];
    ushort*       Co[3];
};

__global__ __launch_bounds__(256) void gemm_qkv(QkvArgs qa, int M, int N, int Kd)
{
    int brow, bcol;
    swz_block(brow, bcol, 128);
    const int z = blockIdx.z;
    gemm_body<false, 2>(qa.Ah[z], qa.Al[z], qa.Bh[z], qa.Bl[z], qa.bias[z],
                        nullptr, qa.Co[z], nullptr, M, N, Kd, Kd, brow, bcol);
}

// ---------------------------------------------------------------------------
// Split-K=2 GEMM, 256M x 128N tile, 8 waves (r14). Same r10 ring logic with
// re-derived per-wave issue counts: G0=[Ah(2),Bh(1)]=3, G1=[Bl]=1, G2=[Al]=2.
// Deque-derived waits: prologue vmcnt(3); steady 5/4/3; last tile 2/0/-.
// Per-wave sub-tile 64x64 (wave grid 4M x 2N) -> acc[4][4], frag reads and
// MFMA cluster identical to gemm_body. LDS 96KB (A 64 + B 32) -> 1 block/CU.
// z=0 carries bias -> C0, z=1 -> C1. fp32 out; partials combined in add_ln3.
// ---------------------------------------------------------------------------
__global__ __launch_bounds__(512) void gemm_sk2_256(
        const ushort* __restrict__ Ah_, const ushort* __restrict__ Al_,
        const ushort* __restrict__ Bh_, const ushort* __restrict__ Bl_,
        const float* __restrict__ bias_,
        float* __restrict__ C0, float* __restrict__ C1,
        int M, int N, int Kd)
{
    __shared__ __align__(16) ushort SA[2][2][256 * 32];  // Ah, Al : 64KB
    __shared__ __align__(16) ushort SB[2][2][128 * 32];  // Bh, Bl : 32KB

    const int z   = blockIdx.z;
    const int Kh2 = Kd >> 1;
    const int ko  = z * Kh2;
    const ushort* Ah = Ah_ + ko;
    const ushort* Al = Al_ + ko;
    const ushort* Bh = Bh_ + ko;
    const ushort* Bl = Bl_ + ko;
    const float*  bias = (z == 0) ? bias_ : nullptr;
    float* C = (z == 0) ? C0 : C1;

    const int t    = threadIdx.x;
    const int lane = t & 63;
    const int w    = t >> 6;
    const int wr   = (w >> 1) * 64;    // 4 M-quads (0..192)
    const int wc   = (w & 1) * 64;     // 2 N-halves (0/64)
    const int fr   = lane & 15;
    const int g    = lane >> 4;
    const int sS   = ((g ^ ((fr >> 1) & 3)) << 3);
    const int cl   = lane & 15;
    const int rq   = (lane >> 4) * 4;

    int brow, bcol;
    {
        const int nx  = gridDim.x;
        const int lin = blockIdx.y * nx + blockIdx.x;
        const int cpx = (nx * gridDim.y) >> 3;
        const int swz = (lin & 7) * cpx + (lin >> 3);
        brow = (swz / nx) * 256;
        bcol = (swz % nx) * 128;
    }

    float bpre[4];
    #pragma unroll
    for (int j = 0; j < 4; ++j)
        bpre[j] = bias ? bias[bcol + wc + j * 16 + cl] : 0.f;

    f32x4_t acc[4][4];
    #pragma unroll
    for (int i = 0; i < 4; ++i)
        #pragma unroll
        for (int j = 0; j < 4; ++j)
            acc[i][j] = (f32x4_t){0.f, 0.f, 0.f, 0.f};

    const int lrow  = lane >> 2;
    const int lslot = ((lane & 3) ^ ((lane >> 3) & 3)) << 3;
    const int cA0   = w * 2;   // A: 16 chunks over 8 waves (2 each)

    auto issueA = [&](const ushort* gpp, int pl, int buf, int k0) {
        #pragma unroll
        for (int ii = 0; ii < 2; ++ii) {
            int c = cA0 + ii;
            gl_lds16(gpp + (size_t)(brow + c * 16 + lrow) * Kd + k0 + lslot,
                     &SA[buf][pl][c * 512]);
        }
    };
    auto issueB = [&](const ushort* gpp, int pl, int buf, int k0) {
        gl_lds16(gpp + (size_t)(bcol + w * 16 + lrow) * Kd + k0 + lslot,
                 &SB[buf][pl][w * 512]);
    };

    bf16x8_t ahf[4], bhf[4], blf[4], alf[4];

    // prologue: tile 0 -> buf 0; issue order G0=[Ah(2),Bh(1)], G1=[Bl(1)], G2=[Al(2)]
    issueA(Ah, 0, 0, 0);
    issueB(Bh, 0, 0, 0);
    issueB(Bl, 1, 0, 0);
    issueA(Al, 1, 0, 0);
    asm volatile("s_waitcnt vmcnt(3)" ::: "memory");   // G0 done (bias drains too)
    __builtin_amdgcn_s_barrier();

    const int NT = Kh2 >> 5;
    for (int tt = 0; tt < NT; ++tt) {
        const int cur = tt & 1, nxt = cur ^ 1;
        const int kn  = (tt + 1) << 5;
        const bool more = (tt + 1 < NT);

        // phase 0: hh — read Ah,Bh(cur); issue G0(t+1); confirm G1(t)
        #pragma unroll
        for (int i = 0; i < 4; ++i)
            ahf[i] = *(const bf16x8_t*)&SA[cur][0][(wr + i * 16 + fr) * 32 + sS];
        #pragma unroll
        for (int j = 0; j < 4; ++j)
            bhf[j] = *(const bf16x8_t*)&SB[cur][0][(wc + j * 16 + fr) * 32 + sS];
        if (more) {
            issueA(Ah, 0, nxt, kn);
            issueB(Bh, 0, nxt, kn);
            asm volatile("s_waitcnt vmcnt(5)" ::: "memory");
        } else {
            asm volatile("s_waitcnt vmcnt(2)" ::: "memory");
        }
        __builtin_amdgcn_s_barrier();
        asm volatile("s_waitcnt lgkmcnt(0)" ::: "memory");
        __builtin_amdgcn_sched_barrier(0);
        __builtin_amdgcn_s_setprio(1);
        #pragma unroll
        for (int i = 0; i < 4; ++i)
            #pragma unroll
            for (int j = 0; j < 4; ++j)
                acc[i][j] = __builtin_amdgcn_mfma_f32_16x16x32_bf16(ahf[i], bhf[j], acc[i][j], 0, 0, 0);
        __builtin_amdgcn_s_setprio(0);
        __builtin_amdgcn_s_barrier();

        // phase 1: hl — read Bl(cur); issue G1(t+1); confirm G2(t)
        #pragma unroll
        for (int j = 0; j < 4; ++j)
            blf[j] = *(const bf16x8_t*)&SB[cur][1][(wc + j * 16 + fr) * 32 + sS];
        if (more) {
            issueB(Bl, 1, nxt, kn);
            asm volatile("s_waitcnt vmcnt(4)" ::: "memory");
        } else {
            asm volatile("s_waitcnt vmcnt(0)" ::: "memory");
        }
        __builtin_amdgcn_s_barrier();
        asm volatile("s_waitcnt lgkmcnt(0)" ::: "memory");
        __builtin_amdgcn_sched_barrier(0);
        __builtin_amdgcn_s_setprio(1);
        #pragma unroll
        for (int i = 0; i < 4; ++i)
            #pragma unroll
            for (int j = 0; j < 4; ++j)
                acc[i][j] = __builtin_amdgcn_mfma_f32_16x16x32_bf16(ahf[i], blf[j], acc[i][j], 0, 0, 0);
        __builtin_amdgcn_s_setprio(0);
        __builtin_amdgcn_s_barrier();

        // phase 2: lh — read Al(cur); issue G2(t+1); confirm G0(t+1)
        #pragma unroll
        for (int i = 0; i < 4; ++i)
            alf[i] = *(const bf16x8_t*)&SA[cur][1][(wr + i * 16 + fr) * 32 + sS];
        if (more) {
            issueA(Al, 1, nxt, kn);
            asm volatile("s_waitcnt vmcnt(3)" ::: "memory");
        }
        __builtin_amdgcn_s_barrier();
        asm volatile("s_waitcnt lgkmcnt(0)" ::: "memory");
        __builtin_amdgcn_sched_barrier(0);
        __builtin_amdgcn_s_setprio(1);
        #pragma unroll
        for (int i = 0; i < 4; ++i)
            #pragma unroll
            for (int j = 0; j < 4; ++j)
                acc[i][j] = __builtin_amdgcn_mfma_f32_16x16x32_bf16(alf[i], bhf[j], acc[i][j], 0, 0, 0);
        __builtin_amdgcn_s_setprio(0);
        __builtin_amdgcn_s_barrier();
    }

    // epilogue: fp32 partials (same as gemm_body OMODE 0)
    #pragma unroll
    for (int j = 0; j < 4; ++j) {
        int col = bcol + wc + j * 16 + cl;
        #pragma unroll
        for (int i = 0; i < 4; ++i)
            #pragma unroll
            for (int r = 0; r < 4; ++r) {
                int row = brow + wr + i * 16 + rq + r;
                C[(size_t)row * N + col] = acc[i][j][r] + bpre[j];
            }
    }
}

// ---------------------------------------------------------------------------
// FFN1 (validated r13): 256^2 tile, 8 waves, r10 ring (6/6/4; 2/0/-).
// ---------------------------------------------------------------------------
__global__ __launch_bounds__(512) void gemm_ffn1_256(
        const ushort* __restrict__ Ah, const ushort* __restrict__ Al,
        const ushort* __restrict__ Bh, const ushort* __restrict__ Bl,
        const float* __restrict__ bias,
        ushort* __restrict__ Ch, ushort* __restrict__ Cl,
        int M, int N, int Kd)
{
    __shared__ __align__(16) ushort S[2][4][256 * 32];   // 128KB

    const int t    = threadIdx.x;
    const int lane = t & 63;
    const int w    = t >> 6;
    const int wr   = (w >> 2) * 128;
    const int wc   = (w & 3) * 64;
    const int fr   = lane & 15;
    const int g    = lane >> 4;
    const int sS   = ((g ^ ((fr >> 1) & 3)) << 3);
    const int cl   = lane & 15;
    const int rq   = (lane >> 4) * 4;

    int brow, bcol;
    swz_block(brow, bcol, 256);

    float bpre[4];
    #pragma unroll
    for (int j = 0; j < 4; ++j) bpre[j] = bias[bcol + wc + j * 16 + cl];

    f32x4_t acc[8][4];
    #pragma unroll
    for (int i = 0; i < 8; ++i)
        #pragma unroll
        for (int j = 0; j < 4; ++j)
            acc[i][j] = (f32x4_t){0.f, 0.f, 0.f, 0.f};

    const int lrow  = lane >> 2;
    const int lslot = ((lane & 3) ^ ((lane >> 3) & 3)) << 3;
    const int c0    = w * 2;

    auto issue2 = [&](const ushort* gpp, int rb, int pl, int buf, int k0) {
        #pragma unroll
        for (int ii = 0; ii < 2; ++ii) {
            int c = c0 + ii;
            gl_lds16(gpp + (size_t)(rb + c * 16 + lrow) * Kd + k0 + lslot,
                     &S[buf][pl][c * 512]);
        }
    };

    bf16x8_t ahf[8], bhf[4], blf[4], alf[8];

    issue2(Ah, brow, 0, 0, 0);
    issue2(Bh, bcol, 2, 0, 0);
    issue2(Bl, bcol, 3, 0, 0);
    issue2(Al, brow, 1, 0, 0);
    asm volatile("s_waitcnt vmcnt(4)" ::: "memory");
    __builtin_amdgcn_s_barrier();

    const int NT = Kd >> 5;
    for (int tt = 0; tt < NT; ++tt) {
        const int cur = tt & 1, nxt = cur ^ 1;
        const int kn  = (tt + 1) << 5;
        const bool more = (tt + 1 < NT);

        // phase 0: hh
        #pragma unroll
        for (int i = 0; i < 8; ++i)
            ahf[i] = *(const bf16x8_t*)&S[cur][0][(wr + i * 16 + fr) * 32 + sS];
        #pragma unroll
        for (int j = 0; j < 4; ++j)
            bhf[j] = *(const bf16x8_t*)&S[cur][2][(wc + j * 16 + fr) * 32 + sS];
        if (more) {
            issue2(Ah, brow, 0, nxt, kn);
            issue2(Bh, bcol, 2, nxt, kn);
            asm volatile("s_waitcnt vmcnt(6)" ::: "memory");
        } else {
            asm volatile("s_waitcnt vmcnt(2)" ::: "memory");
        }
        __builtin_amdgcn_s_barrier();
        asm volatile("s_waitcnt lgkmcnt(0)" ::: "memory");
        __builtin_amdgcn_sched_barrier(0);
        __builtin_amdgcn_s_setprio(1);
        #pragma unroll
        for (int i = 0; i < 8; ++i)
            #pragma unroll
            for (int j = 0; j < 4; ++j)
                acc[i][j] = __builtin_amdgcn_mfma_f32_16x16x32_bf16(ahf[i], bhf[j], acc[i][j], 0, 0, 0);
        __builtin_amdgcn_s_setprio(0);
        __builtin_amdgcn_s_barrier();

        // phase 1: hl
        #pragma unroll
        for (int j = 0; j < 4; ++j)
            blf[j] = *(const bf16x8_t*)&S[cur][3][(wc + j * 16 + fr) * 32 + sS];
        if (more) {
            issue2(Bl, bcol, 3, nxt, kn);
            asm volatile("s_waitcnt vmcnt(6)" ::: "memory");
        } else {
            asm volatile("s_waitcnt vmcnt(0)" ::: "memory");
        }
        __builtin_amdgcn_s_barrier();
        asm volatile("s_waitcnt lgkmcnt(0)" ::: "memory");
        __builtin_amdgcn_sched_barrier(0);
        __builtin_amdgcn_s_setprio(1);
        #pragma unroll
        for (int i = 0; i < 8; ++i)
            #pragma unroll
            for (int j = 0; j < 4; ++j)
                acc[i][j] = __builtin_amdgcn_mfma_f32_16x16x32_bf16(ahf[i], blf[j], acc[i][j], 0, 0, 0);
        __builtin_amdgcn_s_setprio(0);
        __builtin_amdgcn_s_barrier();

        // phase 2: lh
        #pragma unroll
        for (int i = 0; i < 8; ++i)
            alf[i] = *(const bf16x8_t*)&S[cur][1][(wr + i * 16 + fr) * 32 + sS];
        if (more) {
            issue2(Al, brow, 1, nxt, kn);
            asm volatile("s_waitcnt vmcnt(4)" ::: "memory");
        }
        __builtin_amdgcn_s_barrier();
        asm volatile("s_waitcnt lgkmcnt(0)" ::: "memory");
        __builtin_amdgcn_sched_barrier(0);
        __builtin_amdgcn_s_setprio(1);
        #pragma unroll
        for (int i = 0; i < 8; ++i)
            #pragma unroll
            for (int j = 0; j < 4; ++j)
                acc[i][j] = __builtin_amdgcn_mfma_f32_16x16x32_bf16(alf[i], bhf[j], acc[i][j], 0, 0, 0);
        __builtin_amdgcn_s_setprio(0);
        __builtin_amdgcn_s_barrier();
    }

    __syncthreads();
    float* E = (float*)&S[0][0][0] + w * 4096;
    const int rr8 = lane >> 3;
    const int c8  = (lane & 7) * 8;
    #pragma unroll
    for (int pass = 0; pass < 2; ++pass) {
        #pragma unroll
        for (int i = 0; i < 4; ++i) {
            #pragma unroll
            for (int j = 0; j < 4; ++j)
                #pragma unroll
                for (int r = 0; r < 4; ++r) {
                    float v = fmaxf(acc[pass * 4 + i][j][r] + bpre[j], 0.f);
                    E[(i * 16 + rq + r) * 64 + j * 16 + cl] = v;
                }
        }
        #pragma unroll
        for (int p = 0; p < 8; ++p) {
            int rl = p * 8 + rr8;
            float4 va = *(float4*)&E[rl * 64 + c8];
            float4 vb = *(float4*)&E[rl * 64 + c8 + 4];
            float v[8] = {va.x, va.y, va.z, va.w, vb.x, vb.y, vb.z, vb.w};
            bf16x8_t hv, lv;
            #pragma unroll
            for (int q = 0; q < 8; ++q) {
                ushort hh = f2bf_rne(v[q]);
                hv[q] = (short)hh;
                lv[q] = (short)f2bf_rne(v[q] - bf2f(hh));
            }
            size_t o = (size_t)(brow + wr + pass * 64 + rl) * N + (bcol + wc + c8);
            *(bf16x8_t*)&Ch[o] = hv;
            *(bf16x8_t*)&Cl[o] = lv;
        }
    }
}

// ---------------------------------------------------------------------------
// MFMA flash attention v2 (r12-validated): swapped operands, per-lane
// softmax state, T14 reg prefetch, coalesced transposed epilogue.
// ---------------------------------------------------------------------------
__global__ __launch_bounds__(256) void flash_attn_mfma(
        const ushort* __restrict__ qh, const ushort* __restrict__ kh,
        const ushort* __restrict__ vh,
        ushort* __restrict__ Oh, ushort* __restrict__ Ol)
{
    __shared__ __align__(16) ushort SMEM[8192];
    ushort* sk  = SMEM;
    ushort* svt = SMEM + 2304;
    ushort* pw0 = SMEM + 4864;

    const int bid  = blockIdx.x;
    const int slot = bid >> 3;
    const int bh   = (bid & 7) * 8 + (slot >> 4);
    const int qt   = slot & 15;
    const int b    = bh >> 4;
    const int h    = bh & 15;
    const int qb   = qt * 64;

    const int t = threadIdx.x, lane = t & 63, w = t >> 6;
    const int l15 = lane & 15, g = lane >> 4;

    bf16x8_t qf[2];
    {
        size_t qrow = ((size_t)(b * NQ_) + qb + w * 16 + l15) * D_ + h * DH_;
        qf[0] = *(const bf16x8_t*)&qh[qrow + 0  + 8 * g];
        qf[1] = *(const bf16x8_t*)&qh[qrow + 32 + 8 * g];
    }

    f32x4_t acc[4];
    #pragma unroll
    for (int dt = 0; dt < 4; ++dt) acc[dt] = (f32x4_t){0.f, 0.f, 0.f, 0.f};
    float m = -INFINITY, l = 0.0f;

    const int kkv = t >> 3,  kds = (t & 7) * 8;
    const int vkv = t & 31,  vds = (t >> 5) * 8;
    const size_t kvbase = (size_t)(b * NK_) * D_ + h * DH_;

    bf16x8_t kreg = *(const bf16x8_t*)&kh[kvbase + (size_t)kkv * D_ + kds];
    bf16x8_t vreg = *(const bf16x8_t*)&vh[kvbase + (size_t)vkv * D_ + vds];

    ushort* pw = pw0 + w * 640;

    for (int kt = 0; kt < NK_; kt += 32) {
        __syncthreads();
        *(bf16x8_t*)&sk[kkv * 72 + kds] = kreg;
        #pragma unroll
        for (int j = 0; j < 8; ++j)
            svt[(vds + j) * 40 + vkv] = (ushort)vreg[j];
        __syncthreads();
        if (kt + 32 < NK_) {
            kreg = *(const bf16x8_t*)&kh[kvbase + (size_t)(kt + 32 + kkv) * D_ + kds];
            vreg = *(const bf16x8_t*)&vh[kvbase + (size_t)(kt + 32 + vkv) * D_ + vds];
        }

        f32x4_t s0 = (f32x4_t){0.f,0.f,0.f,0.f};
        f32x4_t s1 = (f32x4_t){0.f,0.f,0.f,0.f};
        #pragma unroll
        for (int c = 0; c < 2; ++c) {
            bf16x8_t k0 = *(const bf16x8_t*)&sk[(l15     ) * 72 + 32 * c + 8 * g];
            bf16x8_t k1 = *(const bf16x8_t*)&sk[(l15 + 16) * 72 + 32 * c + 8 * g];
            s0 = __builtin_amdgcn_mfma_f32_16x16x32_bf16(k0, qf[c], s0, 0, 0, 0);
            s1 = __builtin_amdgcn_mfma_f32_16x16x32_bf16(k1, qf[c], s1, 0, 0, 0);
        }

        float e0[4], e1[4];
        #pragma unroll
        for (int r = 0; r < 4; ++r) { e0[r] = s0[r] * SCALE_; e1[r] = s1[r] * SCALE_; }
        float tmax = fmaxf(fmaxf(fmaxf(e0[0], e0[1]), fmaxf(e0[2], e0[3])),
                           fmaxf(fmaxf(e1[0], e1[1]), fmaxf(e1[2], e1[3])));
        tmax = fmaxf(tmax, __shfl_xor(tmax, 16, 64));
        tmax = fmaxf(tmax, __shfl_xor(tmax, 32, 64));
        float mn   = fmaxf(m, tmax);
        float corr = __expf(m - mn);
        float p0[4], p1[4];
        float ps = 0.f;
        #pragma unroll
        for (int r = 0; r < 4; ++r) {
            p0[r] = __expf(e0[r] - mn);
            p1[r] = __expf(e1[r] - mn);
            ps += p0[r] + p1[r];
        }
        ps += __shfl_xor(ps, 16, 64);
        ps += __shfl_xor(ps, 32, 64);
        l = l * corr + ps;
        m = mn;
        #pragma unroll
        for (int dt = 0; dt < 4; ++dt)
            #pragma unroll
            for (int r = 0; r < 4; ++r)
                acc[dt][r] *= corr;

        ushort4 pk0, pk1;
        pk0.x = f2bf_rne(p0[0]); pk0.y = f2bf_rne(p0[1]);
        pk0.z = f2bf_rne(p0[2]); pk0.w = f2bf_rne(p0[3]);
        pk1.x = f2bf_rne(p1[0]); pk1.y = f2bf_rne(p1[1]);
        pk1.z = f2bf_rne(p1[2]); pk1.w = f2bf_rne(p1[3]);
        *(ushort4*)&pw[l15 * 40 + 4 * g]      = pk0;
        *(ushort4*)&pw[l15 * 40 + 16 + 4 * g] = pk1;
        bf16x8_t pa = *(const bf16x8_t*)&pw[l15 * 40 + 8 * g];

        #pragma unroll
        for (int dt = 0; dt < 4; ++dt) {
            bf16x8_t vf = *(const bf16x8_t*)&svt[(16 * dt + l15) * 40 + 8 * g];
            acc[dt] = __builtin_amdgcn_mfma_f32_16x16x32_bf16(vf, pa, acc[dt], 0, 0, 0);
        }
    }

    __syncthreads();
    float invl = 1.0f / l;
    float* Ew = (float*)SMEM + w * 1024;
    #pragma unroll
    for (int dt = 0; dt < 4; ++dt)
        #pragma unroll
        for (int r = 0; r < 4; ++r)
            Ew[(16 * dt + 4 * g + r) * 16 + l15] = acc[dt][r] * invl;
    const int ql = lane >> 2;
    const int dc = (lane & 3) * 16;
    float ov[16];
    #pragma unroll
    for (int j = 0; j < 16; ++j) ov[j] = Ew[(dc + j) * 16 + ql];
    bf16x8_t hv0, hv1, lv0, lv1;
    #pragma unroll
    for (int j = 0; j < 8; ++j) {
        ushort ha = f2bf_rne(ov[j]);
        ushort hb = f2bf_rne(ov[8 + j]);
        hv0[j] = (short)ha; lv0[j] = (short)f2bf_rne(ov[j] - bf2f(ha));
        hv1[j] = (short)hb; lv1[j] = (short)f2bf_rne(ov[8 + j] - bf2f(hb));
    }
    size_t orow = ((size_t)(b * NQ_) + qb + w * 16 + ql) * D_ + h * DH_ + dc;
    *(bf16x8_t*)&Oh[orow]     = hv0;
    *(bf16x8_t*)&Oh[orow + 8] = hv1;
    *(bf16x8_t*)&Ol[orow]     = lv0;
    *(bf16x8_t*)&Ol[orow + 8] = lv1;
}

// ---------------------------------------------------------------------------
// out = LayerNorm(a0 + a1 + r) * g + be. SPLIT: also emit bf16 hi/lo planes.
// ---------------------------------------------------------------------------
template<bool SPLIT>
__global__ __launch_bounds__(256) void add_ln3(const float* __restrict__ a0,
        const float* __restrict__ a1, const float* __restrict__ r,
        const float* __restrict__ g, const float* __restrict__ be,
        float* __restrict__ out, ushort* __restrict__ oh, ushort* __restrict__ ol)
{
    const int row = blockIdx.x;
    const int t = threadIdx.x;
    float vals[4];
    float s1 = 0.0f, s2 = 0.0f;
    #pragma unroll
    for (int i = 0; i < 4; ++i) {
        int col = t + i * 256;
        size_t o = (size_t)row * D_ + col;
        float vv = a0[o] + a1[o] + r[o];
        vals[i] = vv;
        s1 += vv;
        s2 += vv * vv;
    }
    #pragma unroll
    for (int off = 32; off > 0; off >>= 1) {
        s1 += __shfl_down(s1, off, 64);
        s2 += __shfl_down(s2, off, 64);
    }
    __shared__ float p1[4], p2[4];
    const int wave = t >> 6;
    if ((t & 63) == 0) { p1[wave] = s1; p2[wave] = s2; }
    __syncthreads();
    s1 = p1[0] + p1[1] + p1[2] + p1[3];
    s2 = p2[0] + p2[1] + p2[2] + p2[3];
    const float mean = s1 * (1.0f / D_);
    const float var  = s2 * (1.0f / D_) - mean * mean;
    const float rstd = rsqrtf(var + LN_EPS_);
    #pragma unroll
    for (int i = 0; i < 4; ++i) {
        int col = t + i * 256;
        float v = (vals[i] - mean) * rstd * g[col] + be[col];
        out[(size_t)row * D_ + col] = v;
        if (SPLIT) {
            ushort h = f2bf_rne(v);
            oh[(size_t)row * D_ + col] = h;
            ol[(size_t)row * D_ + col] = f2bf_rne(v - bf2f(h));
        }
    }
}

// ---------------------------------------------------------------------------
extern "C" void kernel_launch(void* const* d_in, const int* in_sizes, int n_in,
                              void* d_out, int out_size, void* d_ws, size_t ws_size,
                              hipStream_t stream)
{
    const float* Q   = (const float*)d_in[0];
    const float* K   = (const float*)d_in[1];
    const float* Wq  = (const float*)d_in[2];
    const float* bq  = (const float*)d_in[3];
    const float* Wk  = (const float*)d_in[4];
    const float* bk  = (const float*)d_in[5];
    const float* Wv  = (const float*)d_in[6];
    const float* bv  = (const float*)d_in[7];
    const float* Wo  = (const float*)d_in[8];
    const float* bo  = (const float*)d_in[9];
    const float* W1  = (const float*)d_in[10];
    const float* b1  = (const float*)d_in[11];
    const float* W2  = (const float*)d_in[12];
    const float* b2  = (const float*)d_in[13];
    const float* g0  = (const float*)d_in[14];
    const float* be0 = (const float*)d_in[15];
    const float* g1  = (const float*)d_in[16];
    const float* be1 = (const float*)d_in[17];

    unsigned char* Wb = (unsigned char*)d_ws;
    const size_t MBy = 1ull << 20;

    ushort* Qh   = (ushort*)(Wb +  0 * MBy);
    ushort* Ql   = (ushort*)(Wb +  8 * MBy);
    ushort* Kh   = (ushort*)(Wb + 16 * MBy);
    ushort* Kl   = (ushort*)(Wb + 24 * MBy);
    ushort* Wqh  = (ushort*)(Wb + 32 * MBy);
    ushort* Wql  = (ushort*)(Wb + 34 * MBy);
    ushort* Wkh  = (ushort*)(Wb + 36 * MBy);
    ushort* Wkl  = (ushort*)(Wb + 38 * MBy);
    ushort* Wvh  = (ushort*)(Wb + 40 * MBy);
    ushort* Wvl  = (ushort*)(Wb + 42 * MBy);
    ushort* Woh  = (ushort*)(Wb + 44 * MBy);
    ushort* Wol  = (ushort*)(Wb + 46 * MBy);
    ushort* qhp  = (ushort*)(Wb + 48 * MBy);
    ushort* khp  = (ushort*)(Wb + 56 * MBy);
    ushort* vhp  = (ushort*)(Wb + 64 * MBy);
    ushort* aOh  = (ushort*)(Wb + 72 * MBy);
    ushort* aOl  = (ushort*)(Wb + 80 * MBy);

    float*  oprj0 = (float*)(Wb + 16 * MBy);
    float*  oprj1 = (float*)(Wb + 56 * MBy);
    float*  Xf    = (float*)(Wb +  0 * MBy);
    ushort* Xh    = (ushort*)(Wb + 32 * MBy);
    ushort* Xl    = (ushort*)(Wb + 40 * MBy);
    ushort* W1h   = (ushort*)(Wb + 16 * MBy);
    ushort* W1l   = (ushort*)(Wb + 24 * MBy);
    ushort* Hih   = (ushort*)(Wb + 80 * MBy);   // 32MB: 80-112
    ushort* Hil   = (ushort*)(Wb + 48 * MBy);   // 32MB: 48-80
    ushort* W2h   = (ushort*)(Wb + 16 * MBy);
    ushort* W2l   = (ushort*)(Wb + 24 * MBy);
    float*  Y0    = (float*)(Wb + 32 * MBy);
    float*  Y1    = (float*)d_out;              // scratch until final LN

    const int M = B_ * NQ_;
    const int n4act = M * D_ / 4;
    dim3 blk(256);
    dim3 gQKV(D_ / 128, M / 128, 3);
    dim3 gSK256(D_ / 128, M / 256, 2);          // 8 x 16 x 2 = 256 blocks

    Rows2 r2;
    r2.src[0] = Q; r2.hi[0] = Qh; r2.lo[0] = Ql;
    r2.src[1] = K; r2.hi[1] = Kh; r2.lo[1] = Kl;
    split_rows2<<<dim3(n4act / 256, 1, 2), blk, 0, stream>>>(r2, n4act);

    Tr4 t4;
    t4.w[0] = Wq; t4.th[0] = Wqh; t4.tl[0] = Wql;
    t4.w[1] = Wk; t4.th[1] = Wkh; t4.tl[1] = Wkl;
    t4.w[2] = Wv; t4.th[2] = Wvh; t4.tl[2] = Wvl;
    t4.w[3] = Wo; t4.th[3] = Woh; t4.tl[3] = Wol;
    split_tr4<<<dim3(D_/32, D_/32, 4), blk, 0, stream>>>(t4);

    QkvArgs qa;
    qa.Ah[0] = Qh;  qa.Al[0] = Ql;  qa.Bh[0] = Wqh; qa.Bl[0] = Wql; qa.bias[0] = bq; qa.Co[0] = qhp;
    qa.Ah[1] = Kh;  qa.Al[1] = Kl;  qa.Bh[1] = Wkh; qa.Bl[1] = Wkl; qa.bias[1] = bk; qa.Co[1] = khp;
    qa.Ah[2] = Kh;  qa.Al[2] = Kl;  qa.Bh[2] = Wvh; qa.Bl[2] = Wvl; qa.bias[2] = bv; qa.Co[2] = vhp;
    gemm_qkv<<<gQKV, blk, 0, stream>>>(qa, M, D_, D_);

    flash_attn_mfma<<<dim3(1024), blk, 0, stream>>>(qhp, khp, vhp, aOh, aOl);

    // output projection: split-K=2, 256x128 tile (256 blocks = 1/CU, 8 waves)
    gemm_sk2_256<<<gSK256, dim3(512), 0, stream>>>(aOh, aOl, Woh, Wol, bo,
                                                   oprj0, oprj1, M, D_, D_);
    add_ln3<true><<<M, blk, 0, stream>>>(oprj0, oprj1, Q, g0, be0, Xf, Xh, Xl);

    split_tr<<<dim3(DFF_/32, D_/32), blk, 0, stream>>>(W1, W1h, W1l, D_, DFF_);
    gemm_ffn1_256<<<dim3(DFF_/256, M/256), dim3(512), 0, stream>>>(
        Xh, Xl, W1h, W1l, b1, Hih, Hil, M, DFF_, D_);
    split_tr<<<dim3(D_/32, DFF_/32), blk, 0, stream>>>(W2, W2h, W2l, DFF_, D_);

    // FFN2: split-K=2, 256x128 tile; Y1 uses d_out as scratch
    gemm_sk2_256<<<gSK256, dim3(512), 0, stream>>>(Hih, Hil, W2h, W2l, b2,
                                                   Y0, Y1, M, D_, DFF_);
    add_ln3<false><<<M, blk, 0, stream>>>(Y0, Y1, Xf, g1, be1, (float*)d_out, nullptr, nullptr);
}

// Round 15
// 385.735 us; speedup vs baseline: 1.0443x; 1.0443x over previous
//
#include <hip/hip_runtime.h>
#include <math.h>

#define B_   4
#define NQ_  1024
#define NK_  1024
#define D_   1024
#define H_   16
#define DH_  64
#define DFF_ 4096
#define SCALE_ (1.0f/32.0f)   // 1/sqrt(D)
#define LN_EPS_ 1e-5f

typedef __attribute__((ext_vector_type(8))) short bf16x8_t;  // 8 bf16 = 4 VGPR
typedef __attribute__((ext_vector_type(4))) float f32x4_t;

__device__ __forceinline__ ushort f2bf_rne(float x) {
    unsigned u = __float_as_uint(x);
    unsigned r = (u + 0x7FFFu + ((u >> 16) & 1u)) >> 16;
    return (ushort)r;
}
__device__ __forceinline__ float bf2f(ushort h) {
    return __uint_as_float(((unsigned)h) << 16);
}

// async global->LDS, 16B per lane. LDS dest = wave-uniform base + lane*16.
__device__ __forceinline__ void gl_lds16(const ushort* g, ushort* l) {
    __builtin_amdgcn_global_load_lds(
        (const __attribute__((address_space(1))) unsigned int*)g,
        (__attribute__((address_space(3))) unsigned int*)l, 16, 0, 0);
}

// ---------------------------------------------------------------------------
// fp32 -> (hi,lo) bf16 planes; fused 2-tensor variant (z picks tensor).
// ---------------------------------------------------------------------------
struct Rows2 { const float* src[2]; ushort* hi[2]; ushort* lo[2]; };

__global__ __launch_bounds__(256) void split_rows2(Rows2 a, int n4)
{
    int i = blockIdx.x * 256 + threadIdx.x;
    if (i >= n4) return;
    const int z = blockIdx.z;
    float4 v = ((const float4*)a.src[z])[i];
    ushort4 h, l;
    h.x = f2bf_rne(v.x); l.x = f2bf_rne(v.x - bf2f(h.x));
    h.y = f2bf_rne(v.y); l.y = f2bf_rne(v.y - bf2f(h.y));
    h.z = f2bf_rne(v.z); l.z = f2bf_rne(v.z - bf2f(h.z));
    h.w = f2bf_rne(v.w); l.w = f2bf_rne(v.w - bf2f(h.w));
    ((ushort4*)a.hi[z])[i] = h;
    ((ushort4*)a.lo[z])[i] = l;
}

// ---------------------------------------------------------------------------
// Weight split + transpose: W[K][N] fp32 -> planes Wt[N][K] bf16.
// ---------------------------------------------------------------------------
__device__ __forceinline__ void split_tr_body(const float* __restrict__ Wsrc,
        ushort* __restrict__ th, ushort* __restrict__ tl, int K, int N)
{
    __shared__ float tile[32][33];
    const int nb = blockIdx.x * 32, kb = blockIdx.y * 32;
    const int t = threadIdx.x;
    {
        int r = t >> 3, c4 = (t & 7) * 4;
        float4 v = *(const float4*)&Wsrc[(size_t)(kb + r) * N + nb + c4];
        tile[r][c4 + 0] = v.x; tile[r][c4 + 1] = v.y;
        tile[r][c4 + 2] = v.z; tile[r][c4 + 3] = v.w;
    }
    __syncthreads();
    {
        int n = t >> 3, k4 = (t & 7) * 4;
        float a0 = tile[k4 + 0][n], a1 = tile[k4 + 1][n];
        float a2 = tile[k4 + 2][n], a3 = tile[k4 + 3][n];
        ushort4 h, l;
        h.x = f2bf_rne(a0); l.x = f2bf_rne(a0 - bf2f(h.x));
        h.y = f2bf_rne(a1); l.y = f2bf_rne(a1 - bf2f(h.y));
        h.z = f2bf_rne(a2); l.z = f2bf_rne(a2 - bf2f(h.z));
        h.w = f2bf_rne(a3); l.w = f2bf_rne(a3 - bf2f(h.w));
        size_t o = (size_t)(nb + n) * K + kb + k4;
        *(ushort4*)&th[o] = h;
        *(ushort4*)&tl[o] = l;
    }
}

__global__ __launch_bounds__(256) void split_tr(const float* __restrict__ Wsrc,
        ushort* __restrict__ th, ushort* __restrict__ tl, int K, int N)
{
    split_tr_body(Wsrc, th, tl, K, N);
}

struct Tr4 { const float* w[4]; ushort* th[4]; ushort* tl[4]; };

__global__ __launch_bounds__(256) void split_tr4(Tr4 a)
{
    const int z = blockIdx.z;
    split_tr_body(a.w[z], a.th[z], a.tl[z], D_, D_);
}

// bijective XCD-chunked swizzle (nwg % 8 == 0 for all our grids)
__device__ __forceinline__ void swz_block(int& brow, int& bcol, int tile) {
    const int nx  = gridDim.x;
    const int lin = blockIdx.y * nx + blockIdx.x;
    const int cpx = (nx * gridDim.y) >> 3;
    const int swz = (lin & 7) * cpx + (lin >> 3);
    brow = (swz / nx) * tile;
    bcol = (swz % nx) * tile;
}

// ---------------------------------------------------------------------------
// MFMA GEMM body (r10-validated counted-vmcnt fine-phase pipeline). 128^2.
// ---------------------------------------------------------------------------
template<bool RELU, int OMODE>
__device__ __forceinline__ void gemm_body(
        const ushort* __restrict__ Ah, const ushort* __restrict__ Al,
        const ushort* __restrict__ Bh, const ushort* __restrict__ Bl,
        const float* __restrict__ bias,
        float* __restrict__ C, ushort* __restrict__ Ch, ushort* __restrict__ Cl,
        int M, int N, int Kd, int Klen, int brow, int bcol)
{
    __shared__ __align__(16) ushort S[2][4][128 * 32];   // 64KB dbuf

    const int t    = threadIdx.x;
    const int lane = t & 63;
    const int w    = t >> 6;
    const int wr   = (w >> 1) * 64;
    const int wc   = (w & 1) * 64;
    const int fr   = lane & 15;
    const int g    = lane >> 4;
    const int sS   = ((g ^ ((fr >> 1) & 3)) << 3);
    const int cl   = lane & 15;
    const int rq   = (lane >> 4) * 4;

    float bpre[4];
    #pragma unroll
    for (int j = 0; j < 4; ++j)
        bpre[j] = bias ? bias[bcol + wc + j * 16 + cl] : 0.f;

    f32x4_t acc[4][4];
    #pragma unroll
    for (int i = 0; i < 4; ++i)
        #pragma unroll
        for (int j = 0; j < 4; ++j)
            acc[i][j] = (f32x4_t){0.f, 0.f, 0.f, 0.f};

    const int lrow  = lane >> 2;
    const int lslot = ((lane & 3) ^ ((lane >> 3) & 3)) << 3;
    const int c0    = w * 2;

    auto issue2 = [&](const ushort* gpp, int rb, int pl, int buf, int k0) {
        #pragma unroll
        for (int ii = 0; ii < 2; ++ii) {
            int c = c0 + ii;
            gl_lds16(gpp + (size_t)(rb + c * 16 + lrow) * Kd + k0 + lslot,
                     &S[buf][pl][c * 512]);
        }
    };

    bf16x8_t ahf[4], bhf[4], blf[4], alf[4];

    issue2(Ah, brow, 0, 0, 0);
    issue2(Bh, bcol, 2, 0, 0);
    issue2(Bl, bcol, 3, 0, 0);
    issue2(Al, brow, 1, 0, 0);
    asm volatile("s_waitcnt vmcnt(4)" ::: "memory");
    __builtin_amdgcn_s_barrier();

    const int NT = Klen >> 5;
    for (int tt = 0; tt < NT; ++tt) {
        const int cur = tt & 1, nxt = cur ^ 1;
        const int kn  = (tt + 1) << 5;
        const bool more = (tt + 1 < NT);

        // phase 0: hh
        #pragma unroll
        for (int i = 0; i < 4; ++i)
            ahf[i] = *(const bf16x8_t*)&S[cur][0][(wr + i * 16 + fr) * 32 + sS];
        #pragma unroll
        for (int j = 0; j < 4; ++j)
            bhf[j] = *(const bf16x8_t*)&S[cur][2][(wc + j * 16 + fr) * 32 + sS];
        if (more) {
            issue2(Ah, brow, 0, nxt, kn);
            issue2(Bh, bcol, 2, nxt, kn);
            asm volatile("s_waitcnt vmcnt(6)" ::: "memory");
        } else {
            asm volatile("s_waitcnt vmcnt(2)" ::: "memory");
        }
        __builtin_amdgcn_s_barrier();
        asm volatile("s_waitcnt lgkmcnt(0)" ::: "memory");
        __builtin_amdgcn_sched_barrier(0);
        __builtin_amdgcn_s_setprio(1);
        #pragma unroll
        for (int i = 0; i < 4; ++i)
            #pragma unroll
            for (int j = 0; j < 4; ++j)
                acc[i][j] = __builtin_amdgcn_mfma_f32_16x16x32_bf16(ahf[i], bhf[j], acc[i][j], 0, 0, 0);
        __builtin_amdgcn_s_setprio(0);
        __builtin_amdgcn_s_barrier();

        // phase 1: hl
        #pragma unroll
        for (int j = 0; j < 4; ++j)
            blf[j] = *(const bf16x8_t*)&S[cur][3][(wc + j * 16 + fr) * 32 + sS];
        if (more) {
            issue2(Bl, bcol, 3, nxt, kn);
            asm volatile("s_waitcnt vmcnt(6)" ::: "memory");
        } else {
            asm volatile("s_waitcnt vmcnt(0)" ::: "memory");
        }
        __builtin_amdgcn_s_barrier();
        asm volatile("s_waitcnt lgkmcnt(0)" ::: "memory");
        __builtin_amdgcn_sched_barrier(0);
        __builtin_amdgcn_s_setprio(1);
        #pragma unroll
        for (int i = 0; i < 4; ++i)
            #pragma unroll
            for (int j = 0; j < 4; ++j)
                acc[i][j] = __builtin_amdgcn_mfma_f32_16x16x32_bf16(ahf[i], blf[j], acc[i][j], 0, 0, 0);
        __builtin_amdgcn_s_setprio(0);
        __builtin_amdgcn_s_barrier();

        // phase 2: lh
        #pragma unroll
        for (int i = 0; i < 4; ++i)
            alf[i] = *(const bf16x8_t*)&S[cur][1][(wr + i * 16 + fr) * 32 + sS];
        if (more) {
            issue2(Al, brow, 1, nxt, kn);
            asm volatile("s_waitcnt vmcnt(4)" ::: "memory");
        }
        __builtin_amdgcn_s_barrier();
        asm volatile("s_waitcnt lgkmcnt(0)" ::: "memory");
        __builtin_amdgcn_sched_barrier(0);
        __builtin_amdgcn_s_setprio(1);
        #pragma unroll
        for (int i = 0; i < 4; ++i)
            #pragma unroll
            for (int j = 0; j < 4; ++j)
                acc[i][j] = __builtin_amdgcn_mfma_f32_16x16x32_bf16(alf[i], bhf[j], acc[i][j], 0, 0, 0);
        __builtin_amdgcn_s_setprio(0);
        __builtin_amdgcn_s_barrier();
    }

    if (OMODE == 0) {
        #pragma unroll
        for (int j = 0; j < 4; ++j) {
            int col = bcol + wc + j * 16 + cl;
            #pragma unroll
            for (int i = 0; i < 4; ++i)
                #pragma unroll
                for (int r = 0; r < 4; ++r) {
                    int row = brow + wr + i * 16 + rq + r;
                    float v = acc[i][j][r] + bpre[j];
                    if (RELU) v = fmaxf(v, 0.f);
                    C[(size_t)row * N + col] = v;
                }
        }
    } else {
        float* E = (float*)&S[0][0][0] + w * 4096;   // 16KB per wave
        #pragma unroll
        for (int j = 0; j < 4; ++j) {
            #pragma unroll
            for (int i = 0; i < 4; ++i)
                #pragma unroll
                for (int r = 0; r < 4; ++r) {
                    float v = acc[i][j][r] + bpre[j];
                    if (RELU) v = fmaxf(v, 0.f);
                    E[(i * 16 + rq + r) * 64 + j * 16 + cl] = v;
                }
        }
        __syncthreads();
        const int rr8 = lane >> 3;
        const int c8  = (lane & 7) * 8;
        #pragma unroll
        for (int p = 0; p < 8; ++p) {
            int rl = p * 8 + rr8;
            float4 va = *(float4*)&E[rl * 64 + c8];
            float4 vb = *(float4*)&E[rl * 64 + c8 + 4];
            float v[8] = {va.x, va.y, va.z, va.w, vb.x, vb.y, vb.z, vb.w};
            bf16x8_t hv, lv;
            #pragma unroll
            for (int q = 0; q < 8; ++q) {
                ushort hh = f2bf_rne(v[q]);
                hv[q] = (short)hh;
                lv[q] = (short)f2bf_rne(v[q] - bf2f(hh));
            }
            size_t o = (size_t)(brow + wr + rl) * N + (bcol + wc + c8);
            *(bf16x8_t*)&Ch[o] = hv;
            if (OMODE == 1) *(bf16x8_t*)&Cl[o] = lv;
        }
    }
}

// split-K=2 (validated r11/r13): grid.z picks K-window; z=0 carries bias.
__global__ __launch_bounds__(256) void gemm_splitk2(
        const ushort* __restrict__ Ah, const ushort* __restrict__ Al,
        const ushort* __restrict__ Bh, const ushort* __restrict__ Bl,
        const float* __restrict__ bias,
        float* __restrict__ C0, float* __restrict__ C1,
        int M, int N, int Kd)
{
    int brow, bcol;
    swz_block(brow, bcol, 128);
    const int z = blockIdx.z;
    const int Kh2 = Kd >> 1;
    const int ko  = z * Kh2;
    gemm_body<false, 0>(Ah + ko, Al + ko, Bh + ko, Bl + ko,
                        z == 0 ? bias : nullptr,
                        z == 0 ? C0 : C1, nullptr, nullptr,
                        M, N, Kd, Kh2, brow, bcol);
}

// q/k/v projections fused into one dispatch (grid.z = 3 -> 768 blocks)
struct QkvArgs {
    const ushort* Ah[3]; const ushort* Al[3];
    const ushort* Bh[3]; const ushort* Bl[3];
    const float*  bias[3];
    ushort*       Co[3];
};

__global__ __launch_bounds__(256) void gemm_qkv(QkvArgs qa, int M, int N, int Kd)
{
    int brow, bcol;
    swz_block(brow, bcol, 128);
    const int z = blockIdx.z;
    gemm_body<false, 2>(qa.Ah[z], qa.Al[z], qa.Bh[z], qa.Bl[z], qa.bias[z],
                        nullptr, qa.Co[z], nullptr, M, N, Kd, Kd, brow, bcol);
}

// ---------------------------------------------------------------------------
// FFN1 (validated r13): 256^2 tile, 8 waves, r10 ring (6/6/4; 2/0/-).
// ---------------------------------------------------------------------------
__global__ __launch_bounds__(512) void gemm_ffn1_256(
        const ushort* __restrict__ Ah, const ushort* __restrict__ Al,
        const ushort* __restrict__ Bh, const ushort* __restrict__ Bl,
        const float* __restrict__ bias,
        ushort* __restrict__ Ch, ushort* __restrict__ Cl,
        int M, int N, int Kd)
{
    __shared__ __align__(16) ushort S[2][4][256 * 32];   // 128KB

    const int t    = threadIdx.x;
    const int lane = t & 63;
    const int w    = t >> 6;
    const int wr   = (w >> 2) * 128;
    const int wc   = (w & 3) * 64;
    const int fr   = lane & 15;
    const int g    = lane >> 4;
    const int sS   = ((g ^ ((fr >> 1) & 3)) << 3);
    const int cl   = lane & 15;
    const int rq   = (lane >> 4) * 4;

    int brow, bcol;
    swz_block(brow, bcol, 256);

    float bpre[4];
    #pragma unroll
    for (int j = 0; j < 4; ++j) bpre[j] = bias[bcol + wc + j * 16 + cl];

    f32x4_t acc[8][4];
    #pragma unroll
    for (int i = 0; i < 8; ++i)
        #pragma unroll
        for (int j = 0; j < 4; ++j)
            acc[i][j] = (f32x4_t){0.f, 0.f, 0.f, 0.f};

    const int lrow  = lane >> 2;
    const int lslot = ((lane & 3) ^ ((lane >> 3) & 3)) << 3;
    const int c0    = w * 2;

    auto issue2 = [&](const ushort* gpp, int rb, int pl, int buf, int k0) {
        #pragma unroll
        for (int ii = 0; ii < 2; ++ii) {
            int c = c0 + ii;
            gl_lds16(gpp + (size_t)(rb + c * 16 + lrow) * Kd + k0 + lslot,
                     &S[buf][pl][c * 512]);
        }
    };

    bf16x8_t ahf[8], bhf[4], blf[4], alf[8];

    issue2(Ah, brow, 0, 0, 0);
    issue2(Bh, bcol, 2, 0, 0);
    issue2(Bl, bcol, 3, 0, 0);
    issue2(Al, brow, 1, 0, 0);
    asm volatile("s_waitcnt vmcnt(4)" ::: "memory");
    __builtin_amdgcn_s_barrier();

    const int NT = Kd >> 5;
    for (int tt = 0; tt < NT; ++tt) {
        const int cur = tt & 1, nxt = cur ^ 1;
        const int kn  = (tt + 1) << 5;
        const bool more = (tt + 1 < NT);

        // phase 0: hh
        #pragma unroll
        for (int i = 0; i < 8; ++i)
            ahf[i] = *(const bf16x8_t*)&S[cur][0][(wr + i * 16 + fr) * 32 + sS];
        #pragma unroll
        for (int j = 0; j < 4; ++j)
            bhf[j] = *(const bf16x8_t*)&S[cur][2][(wc + j * 16 + fr) * 32 + sS];
        if (more) {
            issue2(Ah, brow, 0, nxt, kn);
            issue2(Bh, bcol, 2, nxt, kn);
            asm volatile("s_waitcnt vmcnt(6)" ::: "memory");
        } else {
            asm volatile("s_waitcnt vmcnt(2)" ::: "memory");
        }
        __builtin_amdgcn_s_barrier();
        asm volatile("s_waitcnt lgkmcnt(0)" ::: "memory");
        __builtin_amdgcn_sched_barrier(0);
        __builtin_amdgcn_s_setprio(1);
        #pragma unroll
        for (int i = 0; i < 8; ++i)
            #pragma unroll
            for (int j = 0; j < 4; ++j)
                acc[i][j] = __builtin_amdgcn_mfma_f32_16x16x32_bf16(ahf[i], bhf[j], acc[i][j], 0, 0, 0);
        __builtin_amdgcn_s_setprio(0);
        __builtin_amdgcn_s_barrier();

        // phase 1: hl
        #pragma unroll
        for (int j = 0; j < 4; ++j)
            blf[j] = *(const bf16x8_t*)&S[cur][3][(wc + j * 16 + fr) * 32 + sS];
        if (more) {
            issue2(Bl, bcol, 3, nxt, kn);
            asm volatile("s_waitcnt vmcnt(6)" ::: "memory");
        } else {
            asm volatile("s_waitcnt vmcnt(0)" ::: "memory");
        }
        __builtin_amdgcn_s_barrier();
        asm volatile("s_waitcnt lgkmcnt(0)" ::: "memory");
        __builtin_amdgcn_sched_barrier(0);
        __builtin_amdgcn_s_setprio(1);
        #pragma unroll
        for (int i = 0; i < 8; ++i)
            #pragma unroll
            for (int j = 0; j < 4; ++j)
                acc[i][j] = __builtin_amdgcn_mfma_f32_16x16x32_bf16(ahf[i], blf[j], acc[i][j], 0, 0, 0);
        __builtin_amdgcn_s_setprio(0);
        __builtin_amdgcn_s_barrier();

        // phase 2: lh
        #pragma unroll
        for (int i = 0; i < 8; ++i)
            alf[i] = *(const bf16x8_t*)&S[cur][1][(wr + i * 16 + fr) * 32 + sS];
        if (more) {
            issue2(Al, brow, 1, nxt, kn);
            asm volatile("s_waitcnt vmcnt(4)" ::: "memory");
        }
        __builtin_amdgcn_s_barrier();
        asm volatile("s_waitcnt lgkmcnt(0)" ::: "memory");
        __builtin_amdgcn_sched_barrier(0);
        __builtin_amdgcn_s_setprio(1);
        #pragma unroll
        for (int i = 0; i < 8; ++i)
            #pragma unroll
            for (int j = 0; j < 4; ++j)
                acc[i][j] = __builtin_amdgcn_mfma_f32_16x16x32_bf16(alf[i], bhf[j], acc[i][j], 0, 0, 0);
        __builtin_amdgcn_s_setprio(0);
        __builtin_amdgcn_s_barrier();
    }

    __syncthreads();
    float* E = (float*)&S[0][0][0] + w * 4096;
    const int rr8 = lane >> 3;
    const int c8  = (lane & 7) * 8;
    #pragma unroll
    for (int pass = 0; pass < 2; ++pass) {
        #pragma unroll
        for (int i = 0; i < 4; ++i) {
            #pragma unroll
            for (int j = 0; j < 4; ++j)
                #pragma unroll
                for (int r = 0; r < 4; ++r) {
                    float v = fmaxf(acc[pass * 4 + i][j][r] + bpre[j], 0.f);
                    E[(i * 16 + rq + r) * 64 + j * 16 + cl] = v;
                }
        }
        #pragma unroll
        for (int p = 0; p < 8; ++p) {
            int rl = p * 8 + rr8;
            float4 va = *(float4*)&E[rl * 64 + c8];
            float4 vb = *(float4*)&E[rl * 64 + c8 + 4];
            float v[8] = {va.x, va.y, va.z, va.w, vb.x, vb.y, vb.z, vb.w};
            bf16x8_t hv, lv;
            #pragma unroll
            for (int q = 0; q < 8; ++q) {
                ushort hh = f2bf_rne(v[q]);
                hv[q] = (short)hh;
                lv[q] = (short)f2bf_rne(v[q] - bf2f(hh));
            }
            size_t o = (size_t)(brow + wr + pass * 64 + rl) * N + (bcol + wc + c8);
            *(bf16x8_t*)&Ch[o] = hv;
            *(bf16x8_t*)&Cl[o] = lv;
        }
    }
}

// ---------------------------------------------------------------------------
// MFMA flash attention v3 (r15): KVBLK=64. Swapped operands (r12-validated
// layout conventions); halves barriers/shfl-reduces/rescales per kv.
// Per 64-kv tile: 8 QK-MFMA + 8 PV-MFMA; per-lane holds 16 scores.
// LDS: sk[64][72] + svt[64][72] + per-wave P[16][72] = 27.6KB.
// ---------------------------------------------------------------------------
__global__ __launch_bounds__(256) void flash_attn_mfma(
        const ushort* __restrict__ qh, const ushort* __restrict__ kh,
        const ushort* __restrict__ vh,
        ushort* __restrict__ Oh, ushort* __restrict__ Ol)
{
    __shared__ __align__(16) ushort SMEM[13824];   // 27648B
    ushort* sk  = SMEM;            // [64][72]
    ushort* svt = SMEM + 4608;     // [64][72]
    ushort* pw0 = SMEM + 9216;     // 4 x [16][72]

    const int bid  = blockIdx.x;
    const int slot = bid >> 3;
    const int bh   = (bid & 7) * 8 + (slot >> 4);
    const int qt   = slot & 15;
    const int b    = bh >> 4;
    const int h    = bh & 15;
    const int qb   = qt * 64;

    const int t = threadIdx.x, lane = t & 63, w = t >> 6;
    const int l15 = lane & 15, g = lane >> 4;

    bf16x8_t qf[2];
    {
        size_t qrow = ((size_t)(b * NQ_) + qb + w * 16 + l15) * D_ + h * DH_;
        qf[0] = *(const bf16x8_t*)&qh[qrow + 0  + 8 * g];
        qf[1] = *(const bf16x8_t*)&qh[qrow + 32 + 8 * g];
    }

    f32x4_t acc[4];   // O^T[d = 16*dt + 4g + r][q = l15]
    #pragma unroll
    for (int dt = 0; dt < 4; ++dt) acc[dt] = (f32x4_t){0.f, 0.f, 0.f, 0.f};
    float m = -INFINITY, l = 0.0f;

    const int kkv = t >> 2;            // 0..63
    const int kds = (t & 3) * 16;      // 0,16,32,48
    const int vkv = t & 63;            // 0..63
    const int vds = (t >> 6) * 16;     // 0,16,32,48
    const size_t kvbase = (size_t)(b * NK_) * D_ + h * DH_;

    // T14: preload tile 0 into regs
    bf16x8_t kr0 = *(const bf16x8_t*)&kh[kvbase + (size_t)kkv * D_ + kds];
    bf16x8_t kr1 = *(const bf16x8_t*)&kh[kvbase + (size_t)kkv * D_ + kds + 8];
    bf16x8_t vr0 = *(const bf16x8_t*)&vh[kvbase + (size_t)vkv * D_ + vds];
    bf16x8_t vr1 = *(const bf16x8_t*)&vh[kvbase + (size_t)vkv * D_ + vds + 8];

    ushort* pw = pw0 + w * 1152;

    for (int kt = 0; kt < NK_; kt += 64) {
        __syncthreads();                        // prior tile's readers done
        *(bf16x8_t*)&sk[kkv * 72 + kds]     = kr0;
        *(bf16x8_t*)&sk[kkv * 72 + kds + 8] = kr1;
        #pragma unroll
        for (int j = 0; j < 8; ++j) {
            svt[(vds + j)     * 72 + vkv] = (ushort)vr0[j];
            svt[(vds + 8 + j) * 72 + vkv] = (ushort)vr1[j];
        }
        __syncthreads();                        // staged tile visible
        if (kt + 64 < NK_) {                    // prefetch next (hides under compute)
            kr0 = *(const bf16x8_t*)&kh[kvbase + (size_t)(kt + 64 + kkv) * D_ + kds];
            kr1 = *(const bf16x8_t*)&kh[kvbase + (size_t)(kt + 64 + kkv) * D_ + kds + 8];
            vr0 = *(const bf16x8_t*)&vh[kvbase + (size_t)(kt + 64 + vkv) * D_ + vds];
            vr1 = *(const bf16x8_t*)&vh[kvbase + (size_t)(kt + 64 + vkv) * D_ + vds + 8];
        }

        // QK^T swapped: S^T[kv = 16*tq + 4g + r][q = l15]
        f32x4_t s[4];
        #pragma unroll
        for (int tq = 0; tq < 4; ++tq) s[tq] = (f32x4_t){0.f,0.f,0.f,0.f};
        #pragma unroll
        for (int c = 0; c < 2; ++c)
            #pragma unroll
            for (int tq = 0; tq < 4; ++tq) {
                bf16x8_t kf = *(const bf16x8_t*)&sk[(l15 + 16 * tq) * 72 + 32 * c + 8 * g];
                s[tq] = __builtin_amdgcn_mfma_f32_16x16x32_bf16(kf, qf[c], s[tq], 0, 0, 0);
            }

        // per-lane online softmax over 16 scores
        float e[16];
        #pragma unroll
        for (int tq = 0; tq < 4; ++tq)
            #pragma unroll
            for (int r = 0; r < 4; ++r)
                e[4 * tq + r] = s[tq][r] * SCALE_;
        float tmax = e[0];
        #pragma unroll
        for (int i = 1; i < 16; ++i) tmax = fmaxf(tmax, e[i]);
        tmax = fmaxf(tmax, __shfl_xor(tmax, 16, 64));
        tmax = fmaxf(tmax, __shfl_xor(tmax, 32, 64));
        float mn   = fmaxf(m, tmax);
        float corr = __expf(m - mn);
        float p[16];
        float ps = 0.f;
        #pragma unroll
        for (int i = 0; i < 16; ++i) { p[i] = __expf(e[i] - mn); ps += p[i]; }
        ps += __shfl_xor(ps, 16, 64);
        ps += __shfl_xor(ps, 32, 64);
        l = l * corr + ps;
        m = mn;
        #pragma unroll
        for (int dt = 0; dt < 4; ++dt)
            #pragma unroll
            for (int r = 0; r < 4; ++r)
                acc[dt][r] *= corr;

        // P -> per-wave LDS (packed b64); read back as PV B-frags
        #pragma unroll
        for (int tq = 0; tq < 4; ++tq) {
            ushort4 pk;
            pk.x = f2bf_rne(p[4 * tq + 0]); pk.y = f2bf_rne(p[4 * tq + 1]);
            pk.z = f2bf_rne(p[4 * tq + 2]); pk.w = f2bf_rne(p[4 * tq + 3]);
            *(ushort4*)&pw[l15 * 72 + 16 * tq + 4 * g] = pk;
        }
        bf16x8_t pa0 = *(const bf16x8_t*)&pw[l15 * 72 + 8 * g];        // kv 0..31
        bf16x8_t pa1 = *(const bf16x8_t*)&pw[l15 * 72 + 32 + 8 * g];   // kv 32..63

        // PV swapped: O^T[d][q] += V^T[d][kv] * P[q][kv]
        #pragma unroll
        for (int dt = 0; dt < 4; ++dt) {
            bf16x8_t vf0 = *(const bf16x8_t*)&svt[(16 * dt + l15) * 72 + 8 * g];
            bf16x8_t vf1 = *(const bf16x8_t*)&svt[(16 * dt + l15) * 72 + 32 + 8 * g];
            acc[dt] = __builtin_amdgcn_mfma_f32_16x16x32_bf16(vf0, pa0, acc[dt], 0, 0, 0);
            acc[dt] = __builtin_amdgcn_mfma_f32_16x16x32_bf16(vf1, pa1, acc[dt], 0, 0, 0);
        }
    }

    // epilogue: O^T -> O via per-wave LDS bounce, coalesced split-plane stores
    __syncthreads();                     // all waves done with SMEM
    float invl = 1.0f / l;
    float* Ew = (float*)SMEM + w * 1024;   // per-wave [64 d][16 q] f32 (4KB)
    #pragma unroll
    for (int dt = 0; dt < 4; ++dt)
        #pragma unroll
        for (int r = 0; r < 4; ++r)
            Ew[(16 * dt + 4 * g + r) * 16 + l15] = acc[dt][r] * invl;
    const int ql = lane >> 2;            // 0..15 q within wave
    const int dc = (lane & 3) * 16;      // 16-col d chunk
    float ov[16];
    #pragma unroll
    for (int j = 0; j < 16; ++j) ov[j] = Ew[(dc + j) * 16 + ql];
    bf16x8_t hv0, hv1, lv0, lv1;
    #pragma unroll
    for (int j = 0; j < 8; ++j) {
        ushort ha = f2bf_rne(ov[j]);
        ushort hb = f2bf_rne(ov[8 + j]);
        hv0[j] = (short)ha; lv0[j] = (short)f2bf_rne(ov[j] - bf2f(ha));
        hv1[j] = (short)hb; lv1[j] = (short)f2bf_rne(ov[8 + j] - bf2f(hb));
    }
    size_t orow = ((size_t)(b * NQ_) + qb + w * 16 + ql) * D_ + h * DH_ + dc;
    *(bf16x8_t*)&Oh[orow]     = hv0;
    *(bf16x8_t*)&Oh[orow + 8] = hv1;
    *(bf16x8_t*)&Ol[orow]     = lv0;
    *(bf16x8_t*)&Ol[orow + 8] = lv1;
}

// ---------------------------------------------------------------------------
// out = LayerNorm(a0 + a1 + r) * g + be. SPLIT: also emit bf16 hi/lo planes.
// ---------------------------------------------------------------------------
template<bool SPLIT>
__global__ __launch_bounds__(256) void add_ln3(const float* __restrict__ a0,
        const float* __restrict__ a1, const float* __restrict__ r,
        const float* __restrict__ g, const float* __restrict__ be,
        float* __restrict__ out, ushort* __restrict__ oh, ushort* __restrict__ ol)
{
    const int row = blockIdx.x;
    const int t = threadIdx.x;
    float vals[4];
    float s1 = 0.0f, s2 = 0.0f;
    #pragma unroll
    for (int i = 0; i < 4; ++i) {
        int col = t + i * 256;
        size_t o = (size_t)row * D_ + col;
        float vv = a0[o] + a1[o] + r[o];
        vals[i] = vv;
        s1 += vv;
        s2 += vv * vv;
    }
    #pragma unroll
    for (int off = 32; off > 0; off >>= 1) {
        s1 += __shfl_down(s1, off, 64);
        s2 += __shfl_down(s2, off, 64);
    }
    __shared__ float p1[4], p2[4];
    const int wave = t >> 6;
    if ((t & 63) == 0) { p1[wave] = s1; p2[wave] = s2; }
    __syncthreads();
    s1 = p1[0] + p1[1] + p1[2] + p1[3];
    s2 = p2[0] + p2[1] + p2[2] + p2[3];
    const float mean = s1 * (1.0f / D_);
    const float var  = s2 * (1.0f / D_) - mean * mean;
    const float rstd = rsqrtf(var + LN_EPS_);
    #pragma unroll
    for (int i = 0; i < 4; ++i) {
        int col = t + i * 256;
        float v = (vals[i] - mean) * rstd * g[col] + be[col];
        out[(size_t)row * D_ + col] = v;
        if (SPLIT) {
            ushort h = f2bf_rne(v);
            oh[(size_t)row * D_ + col] = h;
            ol[(size_t)row * D_ + col] = f2bf_rne(v - bf2f(h));
        }
    }
}

// ---------------------------------------------------------------------------
extern "C" void kernel_launch(void* const* d_in, const int* in_sizes, int n_in,
                              void* d_out, int out_size, void* d_ws, size_t ws_size,
                              hipStream_t stream)
{
    const float* Q   = (const float*)d_in[0];
    const float* K   = (const float*)d_in[1];
    const float* Wq  = (const float*)d_in[2];
    const float* bq  = (const float*)d_in[3];
    const float* Wk  = (const float*)d_in[4];
    const float* bk  = (const float*)d_in[5];
    const float* Wv  = (const float*)d_in[6];
    const float* bv  = (const float*)d_in[7];
    const float* Wo  = (const float*)d_in[8];
    const float* bo  = (const float*)d_in[9];
    const float* W1  = (const float*)d_in[10];
    const float* b1  = (const float*)d_in[11];
    const float* W2  = (const float*)d_in[12];
    const float* b2  = (const float*)d_in[13];
    const float* g0  = (const float*)d_in[14];
    const float* be0 = (const float*)d_in[15];
    const float* g1  = (const float*)d_in[16];
    const float* be1 = (const float*)d_in[17];

    unsigned char* Wb = (unsigned char*)d_ws;
    const size_t MBy = 1ull << 20;

    ushort* Qh   = (ushort*)(Wb +  0 * MBy);
    ushort* Ql   = (ushort*)(Wb +  8 * MBy);
    ushort* Kh   = (ushort*)(Wb + 16 * MBy);
    ushort* Kl   = (ushort*)(Wb + 24 * MBy);
    ushort* Wqh  = (ushort*)(Wb + 32 * MBy);
    ushort* Wql  = (ushort*)(Wb + 34 * MBy);
    ushort* Wkh  = (ushort*)(Wb + 36 * MBy);
    ushort* Wkl  = (ushort*)(Wb + 38 * MBy);
    ushort* Wvh  = (ushort*)(Wb + 40 * MBy);
    ushort* Wvl  = (ushort*)(Wb + 42 * MBy);
    ushort* Woh  = (ushort*)(Wb + 44 * MBy);
    ushort* Wol  = (ushort*)(Wb + 46 * MBy);
    ushort* qhp  = (ushort*)(Wb + 48 * MBy);
    ushort* khp  = (ushort*)(Wb + 56 * MBy);
    ushort* vhp  = (ushort*)(Wb + 64 * MBy);
    ushort* aOh  = (ushort*)(Wb + 72 * MBy);
    ushort* aOl  = (ushort*)(Wb + 80 * MBy);

    float*  oprj0 = (float*)(Wb + 16 * MBy);
    float*  oprj1 = (float*)(Wb + 56 * MBy);
    float*  Xf    = (float*)(Wb +  0 * MBy);
    ushort* Xh    = (ushort*)(Wb + 32 * MBy);
    ushort* Xl    = (ushort*)(Wb + 40 * MBy);
    ushort* W1h   = (ushort*)(Wb + 16 * MBy);
    ushort* W1l   = (ushort*)(Wb + 24 * MBy);
    ushort* Hih   = (ushort*)(Wb + 80 * MBy);   // 32MB: 80-112
    ushort* Hil   = (ushort*)(Wb + 48 * MBy);   // 32MB: 48-80
    ushort* W2h   = (ushort*)(Wb + 16 * MBy);
    ushort* W2l   = (ushort*)(Wb + 24 * MBy);
    float*  Y0    = (float*)(Wb + 32 * MBy);
    float*  Y1    = (float*)d_out;              // scratch until final LN

    const int M = B_ * NQ_;
    const int n4act = M * D_ / 4;
    dim3 blk(256);
    dim3 gQKV(D_ / 128, M / 128, 3);
    dim3 gSK(D_ / 128, M / 128, 2);

    Rows2 r2;
    r2.src[0] = Q; r2.hi[0] = Qh; r2.lo[0] = Ql;
    r2.src[1] = K; r2.hi[1] = Kh; r2.lo[1] = Kl;
    split_rows2<<<dim3(n4act / 256, 1, 2), blk, 0, stream>>>(r2, n4act);

    Tr4 t4;
    t4.w[0] = Wq; t4.th[0] = Wqh; t4.tl[0] = Wql;
    t4.w[1] = Wk; t4.th[1] = Wkh; t4.tl[1] = Wkl;
    t4.w[2] = Wv; t4.th[2] = Wvh; t4.tl[2] = Wvl;
    t4.w[3] = Wo; t4.th[3] = Woh; t4.tl[3] = Wol;
    split_tr4<<<dim3(D_/32, D_/32, 4), blk, 0, stream>>>(t4);

    QkvArgs qa;
    qa.Ah[0] = Qh;  qa.Al[0] = Ql;  qa.Bh[0] = Wqh; qa.Bl[0] = Wql; qa.bias[0] = bq; qa.Co[0] = qhp;
    qa.Ah[1] = Kh;  qa.Al[1] = Kl;  qa.Bh[1] = Wkh; qa.Bl[1] = Wkl; qa.bias[1] = bk; qa.Co[1] = khp;
    qa.Ah[2] = Kh;  qa.Al[2] = Kl;  qa.Bh[2] = Wvh; qa.Bl[2] = Wvl; qa.bias[2] = bv; qa.Co[2] = vhp;
    gemm_qkv<<<gQKV, blk, 0, stream>>>(qa, M, D_, D_);

    flash_attn_mfma<<<dim3(1024), blk, 0, stream>>>(qhp, khp, vhp, aOh, aOl);

    // output projection, split-K=2 (2 blocks/CU) + fused 3-input LN
    gemm_splitk2<<<gSK, blk, 0, stream>>>(aOh, aOl, Woh, Wol, bo, oprj0, oprj1, M, D_, D_);
    add_ln3<true><<<M, blk, 0, stream>>>(oprj0, oprj1, Q, g0, be0, Xf, Xh, Xl);

    split_tr<<<dim3(DFF_/32, D_/32), blk, 0, stream>>>(W1, W1h, W1l, D_, DFF_);
    gemm_ffn1_256<<<dim3(DFF_/256, M/256), dim3(512), 0, stream>>>(
        Xh, Xl, W1h, W1l, b1, Hih, Hil, M, DFF_, D_);
    split_tr<<<dim3(D_/32, DFF_/32), blk, 0, stream>>>(W2, W2h, W2l, DFF_, D_);

    // FFN2: split-K=2 (proven r13 config); Y1 uses d_out as scratch
    gemm_splitk2<<<gSK, blk, 0, stream>>>(Hih, Hil, W2h, W2l, b2, Y0, Y1, M, D_, DFF_);
    add_ln3<false><<<M, blk, 0, stream>>>(Y0, Y1, Xf, g1, be1, (float*)d_out, nullptr, nullptr);
}

// Round 16
// 381.861 us; speedup vs baseline: 1.0549x; 1.0101x over previous
//
#include <hip/hip_runtime.h>
#include <math.h>

#define B_   4
#define NQ_  1024
#define NK_  1024
#define D_   1024
#define H_   16
#define DH_  64
#define DFF_ 4096
#define SCALE_ (1.0f/32.0f)   // 1/sqrt(D)
#define LN_EPS_ 1e-5f

typedef __attribute__((ext_vector_type(8))) short bf16x8_t;  // 8 bf16 = 4 VGPR
typedef __attribute__((ext_vector_type(4))) float f32x4_t;

__device__ __forceinline__ ushort f2bf_rne(float x) {
    unsigned u = __float_as_uint(x);
    unsigned r = (u + 0x7FFFu + ((u >> 16) & 1u)) >> 16;
    return (ushort)r;
}
__device__ __forceinline__ float bf2f(ushort h) {
    return __uint_as_float(((unsigned)h) << 16);
}

// async global->LDS, 16B per lane. LDS dest = wave-uniform base + lane*16.
__device__ __forceinline__ void gl_lds16(const ushort* g, ushort* l) {
    __builtin_amdgcn_global_load_lds(
        (const __attribute__((address_space(1))) unsigned int*)g,
        (__attribute__((address_space(3))) unsigned int*)l, 16, 0, 0);
}

// ---------------------------------------------------------------------------
// fp32 -> (hi,lo) bf16 planes; fused 2-tensor variant (z picks tensor).
// ---------------------------------------------------------------------------
struct Rows2 { const float* src[2]; ushort* hi[2]; ushort* lo[2]; };

__global__ __launch_bounds__(256) void split_rows2(Rows2 a, int n4)
{
    int i = blockIdx.x * 256 + threadIdx.x;
    if (i >= n4) return;
    const int z = blockIdx.z;
    float4 v = ((const float4*)a.src[z])[i];
    ushort4 h, l;
    h.x = f2bf_rne(v.x); l.x = f2bf_rne(v.x - bf2f(h.x));
    h.y = f2bf_rne(v.y); l.y = f2bf_rne(v.y - bf2f(h.y));
    h.z = f2bf_rne(v.z); l.z = f2bf_rne(v.z - bf2f(h.z));
    h.w = f2bf_rne(v.w); l.w = f2bf_rne(v.w - bf2f(h.w));
    ((ushort4*)a.hi[z])[i] = h;
    ((ushort4*)a.lo[z])[i] = l;
}

// ---------------------------------------------------------------------------
// Weight split + transpose: W[K][N] fp32 -> planes Wt[N][K] bf16.
// ---------------------------------------------------------------------------
__device__ __forceinline__ void split_tr_body(const float* __restrict__ Wsrc,
        ushort* __restrict__ th, ushort* __restrict__ tl, int K, int N)
{
    __shared__ float tile[32][33];
    const int nb = blockIdx.x * 32, kb = blockIdx.y * 32;
    const int t = threadIdx.x;
    {
        int r = t >> 3, c4 = (t & 7) * 4;
        float4 v = *(const float4*)&Wsrc[(size_t)(kb + r) * N + nb + c4];
        tile[r][c4 + 0] = v.x; tile[r][c4 + 1] = v.y;
        tile[r][c4 + 2] = v.z; tile[r][c4 + 3] = v.w;
    }
    __syncthreads();
    {
        int n = t >> 3, k4 = (t & 7) * 4;
        float a0 = tile[k4 + 0][n], a1 = tile[k4 + 1][n];
        float a2 = tile[k4 + 2][n], a3 = tile[k4 + 3][n];
        ushort4 h, l;
        h.x = f2bf_rne(a0); l.x = f2bf_rne(a0 - bf2f(h.x));
        h.y = f2bf_rne(a1); l.y = f2bf_rne(a1 - bf2f(h.y));
        h.z = f2bf_rne(a2); l.z = f2bf_rne(a2 - bf2f(h.z));
        h.w = f2bf_rne(a3); l.w = f2bf_rne(a3 - bf2f(h.w));
        size_t o = (size_t)(nb + n) * K + kb + k4;
        *(ushort4*)&th[o] = h;
        *(ushort4*)&tl[o] = l;
    }
}

__global__ __launch_bounds__(256) void split_tr(const float* __restrict__ Wsrc,
        ushort* __restrict__ th, ushort* __restrict__ tl, int K, int N)
{
    split_tr_body(Wsrc, th, tl, K, N);
}

struct Tr4 { const float* w[4]; ushort* th[4]; ushort* tl[4]; };

__global__ __launch_bounds__(256) void split_tr4(Tr4 a)
{
    const int z = blockIdx.z;
    split_tr_body(a.w[z], a.th[z], a.tl[z], D_, D_);
}

// bijective XCD-chunked swizzle (nwg % 8 == 0 for all our grids)
__device__ __forceinline__ void swz_block(int& brow, int& bcol, int tile) {
    const int nx  = gridDim.x;
    const int lin = blockIdx.y * nx + blockIdx.x;
    const int cpx = (nx * gridDim.y) >> 3;
    const int swz = (lin & 7) * cpx + (lin >> 3);
    brow = (swz / nx) * tile;
    bcol = (swz % nx) * tile;
}

// ---------------------------------------------------------------------------
// MFMA GEMM body (r10-validated counted-vmcnt fine-phase pipeline). 128^2.
// ---------------------------------------------------------------------------
template<bool RELU, int OMODE>
__device__ __forceinline__ void gemm_body(
        const ushort* __restrict__ Ah, const ushort* __restrict__ Al,
        const ushort* __restrict__ Bh, const ushort* __restrict__ Bl,
        const float* __restrict__ bias,
        float* __restrict__ C, ushort* __restrict__ Ch, ushort* __restrict__ Cl,
        int M, int N, int Kd, int Klen, int brow, int bcol)
{
    __shared__ __align__(16) ushort S[2][4][128 * 32];   // 64KB dbuf

    const int t    = threadIdx.x;
    const int lane = t & 63;
    const int w    = t >> 6;
    const int wr   = (w >> 1) * 64;
    const int wc   = (w & 1) * 64;
    const int fr   = lane & 15;
    const int g    = lane >> 4;
    const int sS   = ((g ^ ((fr >> 1) & 3)) << 3);
    const int cl   = lane & 15;
    const int rq   = (lane >> 4) * 4;

    float bpre[4];
    #pragma unroll
    for (int j = 0; j < 4; ++j)
        bpre[j] = bias ? bias[bcol + wc + j * 16 + cl] : 0.f;

    f32x4_t acc[4][4];
    #pragma unroll
    for (int i = 0; i < 4; ++i)
        #pragma unroll
        for (int j = 0; j < 4; ++j)
            acc[i][j] = (f32x4_t){0.f, 0.f, 0.f, 0.f};

    const int lrow  = lane >> 2;
    const int lslot = ((lane & 3) ^ ((lane >> 3) & 3)) << 3;
    const int c0    = w * 2;

    auto issue2 = [&](const ushort* gpp, int rb, int pl, int buf, int k0) {
        #pragma unroll
        for (int ii = 0; ii < 2; ++ii) {
            int c = c0 + ii;
            gl_lds16(gpp + (size_t)(rb + c * 16 + lrow) * Kd + k0 + lslot,
                     &S[buf][pl][c * 512]);
        }
    };

    bf16x8_t ahf[4], bhf[4], blf[4], alf[4];

    issue2(Ah, brow, 0, 0, 0);
    issue2(Bh, bcol, 2, 0, 0);
    issue2(Bl, bcol, 3, 0, 0);
    issue2(Al, brow, 1, 0, 0);
    asm volatile("s_waitcnt vmcnt(4)" ::: "memory");
    __builtin_amdgcn_s_barrier();

    const int NT = Klen >> 5;
    for (int tt = 0; tt < NT; ++tt) {
        const int cur = tt & 1, nxt = cur ^ 1;
        const int kn  = (tt + 1) << 5;
        const bool more = (tt + 1 < NT);

        // phase 0: hh
        #pragma unroll
        for (int i = 0; i < 4; ++i)
            ahf[i] = *(const bf16x8_t*)&S[cur][0][(wr + i * 16 + fr) * 32 + sS];
        #pragma unroll
        for (int j = 0; j < 4; ++j)
            bhf[j] = *(const bf16x8_t*)&S[cur][2][(wc + j * 16 + fr) * 32 + sS];
        if (more) {
            issue2(Ah, brow, 0, nxt, kn);
            issue2(Bh, bcol, 2, nxt, kn);
            asm volatile("s_waitcnt vmcnt(6)" ::: "memory");
        } else {
            asm volatile("s_waitcnt vmcnt(2)" ::: "memory");
        }
        __builtin_amdgcn_s_barrier();
        asm volatile("s_waitcnt lgkmcnt(0)" ::: "memory");
        __builtin_amdgcn_sched_barrier(0);
        __builtin_amdgcn_s_setprio(1);
        #pragma unroll
        for (int i = 0; i < 4; ++i)
            #pragma unroll
            for (int j = 0; j < 4; ++j)
                acc[i][j] = __builtin_amdgcn_mfma_f32_16x16x32_bf16(ahf[i], bhf[j], acc[i][j], 0, 0, 0);
        __builtin_amdgcn_s_setprio(0);
        __builtin_amdgcn_s_barrier();

        // phase 1: hl
        #pragma unroll
        for (int j = 0; j < 4; ++j)
            blf[j] = *(const bf16x8_t*)&S[cur][3][(wc + j * 16 + fr) * 32 + sS];
        if (more) {
            issue2(Bl, bcol, 3, nxt, kn);
            asm volatile("s_waitcnt vmcnt(6)" ::: "memory");
        } else {
            asm volatile("s_waitcnt vmcnt(0)" ::: "memory");
        }
        __builtin_amdgcn_s_barrier();
        asm volatile("s_waitcnt lgkmcnt(0)" ::: "memory");
        __builtin_amdgcn_sched_barrier(0);
        __builtin_amdgcn_s_setprio(1);
        #pragma unroll
        for (int i = 0; i < 4; ++i)
            #pragma unroll
            for (int j = 0; j < 4; ++j)
                acc[i][j] = __builtin_amdgcn_mfma_f32_16x16x32_bf16(ahf[i], blf[j], acc[i][j], 0, 0, 0);
        __builtin_amdgcn_s_setprio(0);
        __builtin_amdgcn_s_barrier();

        // phase 2: lh
        #pragma unroll
        for (int i = 0; i < 4; ++i)
            alf[i] = *(const bf16x8_t*)&S[cur][1][(wr + i * 16 + fr) * 32 + sS];
        if (more) {
            issue2(Al, brow, 1, nxt, kn);
            asm volatile("s_waitcnt vmcnt(4)" ::: "memory");
        }
        __builtin_amdgcn_s_barrier();
        asm volatile("s_waitcnt lgkmcnt(0)" ::: "memory");
        __builtin_amdgcn_sched_barrier(0);
        __builtin_amdgcn_s_setprio(1);
        #pragma unroll
        for (int i = 0; i < 4; ++i)
            #pragma unroll
            for (int j = 0; j < 4; ++j)
                acc[i][j] = __builtin_amdgcn_mfma_f32_16x16x32_bf16(alf[i], bhf[j], acc[i][j], 0, 0, 0);
        __builtin_amdgcn_s_setprio(0);
        __builtin_amdgcn_s_barrier();
    }

    if (OMODE == 0) {
        #pragma unroll
        for (int j = 0; j < 4; ++j) {
            int col = bcol + wc + j * 16 + cl;
            #pragma unroll
            for (int i = 0; i < 4; ++i)
                #pragma unroll
                for (int r = 0; r < 4; ++r) {
                    int row = brow + wr + i * 16 + rq + r;
                    float v = acc[i][j][r] + bpre[j];
                    if (RELU) v = fmaxf(v, 0.f);
                    C[(size_t)row * N + col] = v;
                }
        }
    } else {
        float* E = (float*)&S[0][0][0] + w * 4096;   // 16KB per wave
        #pragma unroll
        for (int j = 0; j < 4; ++j) {
            #pragma unroll
            for (int i = 0; i < 4; ++i)
                #pragma unroll
                for (int r = 0; r < 4; ++r) {
                    float v = acc[i][j][r] + bpre[j];
                    if (RELU) v = fmaxf(v, 0.f);
                    E[(i * 16 + rq + r) * 64 + j * 16 + cl] = v;
                }
        }
        __syncthreads();
        const int rr8 = lane >> 3;
        const int c8  = (lane & 7) * 8;
        #pragma unroll
        for (int p = 0; p < 8; ++p) {
            int rl = p * 8 + rr8;
            float4 va = *(float4*)&E[rl * 64 + c8];
            float4 vb = *(float4*)&E[rl * 64 + c8 + 4];
            float v[8] = {va.x, va.y, va.z, va.w, vb.x, vb.y, vb.z, vb.w};
            bf16x8_t hv, lv;
            #pragma unroll
            for (int q = 0; q < 8; ++q) {
                ushort hh = f2bf_rne(v[q]);
                hv[q] = (short)hh;
                lv[q] = (short)f2bf_rne(v[q] - bf2f(hh));
            }
            size_t o = (size_t)(brow + wr + rl) * N + (bcol + wc + c8);
            *(bf16x8_t*)&Ch[o] = hv;
            if (OMODE == 1) *(bf16x8_t*)&Cl[o] = lv;
        }
    }
}

// split-K=2 (validated r11/r13): grid.z picks K-window; z=0 carries bias.
__global__ __launch_bounds__(256) void gemm_splitk2(
        const ushort* __restrict__ Ah, const ushort* __restrict__ Al,
        const ushort* __restrict__ Bh, const ushort* __restrict__ Bl,
        const float* __restrict__ bias,
        float* __restrict__ C0, float* __restrict__ C1,
        int M, int N, int Kd)
{
    int brow, bcol;
    swz_block(brow, bcol, 128);
    const int z = blockIdx.z;
    const int Kh2 = Kd >> 1;
    const int ko  = z * Kh2;
    gemm_body<false, 0>(Ah + ko, Al + ko, Bh + ko, Bl + ko,
                        z == 0 ? bias : nullptr,
                        z == 0 ? C0 : C1, nullptr, nullptr,
                        M, N, Kd, Kh2, brow, bcol);
}

// q/k/v projections fused into one dispatch (grid.z = 3 -> 768 blocks)
struct QkvArgs {
    const ushort* Ah[3]; const ushort* Al[3];
    const ushort* Bh[3]; const ushort* Bl[3];
    const float*  bias[3];
    ushort*       Co[3];
};

__global__ __launch_bounds__(256) void gemm_qkv(QkvArgs qa, int M, int N, int Kd)
{
    int brow, bcol;
    swz_block(brow, bcol, 128);
    const int z = blockIdx.z;
    gemm_body<false, 2>(qa.Ah[z], qa.Al[z], qa.Bh[z], qa.Bl[z], qa.bias[z],
                        nullptr, qa.Co[z], nullptr, M, N, Kd, Kd, brow, bcol);
}

// ---------------------------------------------------------------------------
// FFN1 (validated r13): 256^2 tile, 8 waves, r10 ring (6/6/4; 2/0/-).
// ---------------------------------------------------------------------------
__global__ __launch_bounds__(512) void gemm_ffn1_256(
        const ushort* __restrict__ Ah, const ushort* __restrict__ Al,
        const ushort* __restrict__ Bh, const ushort* __restrict__ Bl,
        const float* __restrict__ bias,
        ushort* __restrict__ Ch, ushort* __restrict__ Cl,
        int M, int N, int Kd)
{
    __shared__ __align__(16) ushort S[2][4][256 * 32];   // 128KB

    const int t    = threadIdx.x;
    const int lane = t & 63;
    const int w    = t >> 6;
    const int wr   = (w >> 2) * 128;
    const int wc   = (w & 3) * 64;
    const int fr   = lane & 15;
    const int g    = lane >> 4;
    const int sS   = ((g ^ ((fr >> 1) & 3)) << 3);
    const int cl   = lane & 15;
    const int rq   = (lane >> 4) * 4;

    int brow, bcol;
    swz_block(brow, bcol, 256);

    float bpre[4];
    #pragma unroll
    for (int j = 0; j < 4; ++j) bpre[j] = bias[bcol + wc + j * 16 + cl];

    f32x4_t acc[8][4];
    #pragma unroll
    for (int i = 0; i < 8; ++i)
        #pragma unroll
        for (int j = 0; j < 4; ++j)
            acc[i][j] = (f32x4_t){0.f, 0.f, 0.f, 0.f};

    const int lrow  = lane >> 2;
    const int lslot = ((lane & 3) ^ ((lane >> 3) & 3)) << 3;
    const int c0    = w * 2;

    auto issue2 = [&](const ushort* gpp, int rb, int pl, int buf, int k0) {
        #pragma unroll
        for (int ii = 0; ii < 2; ++ii) {
            int c = c0 + ii;
            gl_lds16(gpp + (size_t)(rb + c * 16 + lrow) * Kd + k0 + lslot,
                     &S[buf][pl][c * 512]);
        }
    };

    bf16x8_t ahf[8], bhf[4], blf[4], alf[8];

    issue2(Ah, brow, 0, 0, 0);
    issue2(Bh, bcol, 2, 0, 0);
    issue2(Bl, bcol, 3, 0, 0);
    issue2(Al, brow, 1, 0, 0);
    asm volatile("s_waitcnt vmcnt(4)" ::: "memory");
    __builtin_amdgcn_s_barrier();

    const int NT = Kd >> 5;
    for (int tt = 0; tt < NT; ++tt) {
        const int cur = tt & 1, nxt = cur ^ 1;
        const int kn  = (tt + 1) << 5;
        const bool more = (tt + 1 < NT);

        // phase 0: hh
        #pragma unroll
        for (int i = 0; i < 8; ++i)
            ahf[i] = *(const bf16x8_t*)&S[cur][0][(wr + i * 16 + fr) * 32 + sS];
        #pragma unroll
        for (int j = 0; j < 4; ++j)
            bhf[j] = *(const bf16x8_t*)&S[cur][2][(wc + j * 16 + fr) * 32 + sS];
        if (more) {
            issue2(Ah, brow, 0, nxt, kn);
            issue2(Bh, bcol, 2, nxt, kn);
            asm volatile("s_waitcnt vmcnt(6)" ::: "memory");
        } else {
            asm volatile("s_waitcnt vmcnt(2)" ::: "memory");
        }
        __builtin_amdgcn_s_barrier();
        asm volatile("s_waitcnt lgkmcnt(0)" ::: "memory");
        __builtin_amdgcn_sched_barrier(0);
        __builtin_amdgcn_s_setprio(1);
        #pragma unroll
        for (int i = 0; i < 8; ++i)
            #pragma unroll
            for (int j = 0; j < 4; ++j)
                acc[i][j] = __builtin_amdgcn_mfma_f32_16x16x32_bf16(ahf[i], bhf[j], acc[i][j], 0, 0, 0);
        __builtin_amdgcn_s_setprio(0);
        __builtin_amdgcn_s_barrier();

        // phase 1: hl
        #pragma unroll
        for (int j = 0; j < 4; ++j)
            blf[j] = *(const bf16x8_t*)&S[cur][3][(wc + j * 16 + fr) * 32 + sS];
        if (more) {
            issue2(Bl, bcol, 3, nxt, kn);
            asm volatile("s_waitcnt vmcnt(6)" ::: "memory");
        } else {
            asm volatile("s_waitcnt vmcnt(0)" ::: "memory");
        }
        __builtin_amdgcn_s_barrier();
        asm volatile("s_waitcnt lgkmcnt(0)" ::: "memory");
        __builtin_amdgcn_sched_barrier(0);
        __builtin_amdgcn_s_setprio(1);
        #pragma unroll
        for (int i = 0; i < 8; ++i)
            #pragma unroll
            for (int j = 0; j < 4; ++j)
                acc[i][j] = __builtin_amdgcn_mfma_f32_16x16x32_bf16(ahf[i], blf[j], acc[i][j], 0, 0, 0);
        __builtin_amdgcn_s_setprio(0);
        __builtin_amdgcn_s_barrier();

        // phase 2: lh
        #pragma unroll
        for (int i = 0; i < 8; ++i)
            alf[i] = *(const bf16x8_t*)&S[cur][1][(wr + i * 16 + fr) * 32 + sS];
        if (more) {
            issue2(Al, brow, 1, nxt, kn);
            asm volatile("s_waitcnt vmcnt(4)" ::: "memory");
        }
        __builtin_amdgcn_s_barrier();
        asm volatile("s_waitcnt lgkmcnt(0)" ::: "memory");
        __builtin_amdgcn_sched_barrier(0);
        __builtin_amdgcn_s_setprio(1);
        #pragma unroll
        for (int i = 0; i < 8; ++i)
            #pragma unroll
            for (int j = 0; j < 4; ++j)
                acc[i][j] = __builtin_amdgcn_mfma_f32_16x16x32_bf16(alf[i], bhf[j], acc[i][j], 0, 0, 0);
        __builtin_amdgcn_s_setprio(0);
        __builtin_amdgcn_s_barrier();
    }

    __syncthreads();
    float* E = (float*)&S[0][0][0] + w * 4096;
    const int rr8 = lane >> 3;
    const int c8  = (lane & 7) * 8;
    #pragma unroll
    for (int pass = 0; pass < 2; ++pass) {
        #pragma unroll
        for (int i = 0; i < 4; ++i) {
            #pragma unroll
            for (int j = 0; j < 4; ++j)
                #pragma unroll
                for (int r = 0; r < 4; ++r) {
                    float v = fmaxf(acc[pass * 4 + i][j][r] + bpre[j], 0.f);
                    E[(i * 16 + rq + r) * 64 + j * 16 + cl] = v;
                }
        }
        #pragma unroll
        for (int p = 0; p < 8; ++p) {
            int rl = p * 8 + rr8;
            float4 va = *(float4*)&E[rl * 64 + c8];
            float4 vb = *(float4*)&E[rl * 64 + c8 + 4];
            float v[8] = {va.x, va.y, va.z, va.w, vb.x, vb.y, vb.z, vb.w};
            bf16x8_t hv, lv;
            #pragma unroll
            for (int q = 0; q < 8; ++q) {
                ushort hh = f2bf_rne(v[q]);
                hv[q] = (short)hh;
                lv[q] = (short)f2bf_rne(v[q] - bf2f(hh));
            }
            size_t o = (size_t)(brow + wr + pass * 64 + rl) * N + (bcol + wc + c8);
            *(bf16x8_t*)&Ch[o] = hv;
            *(bf16x8_t*)&Cl[o] = lv;
        }
    }
}

// ---------------------------------------------------------------------------
// MFMA flash attention v3 (r15-validated, KVBLK=64) + r16: setprio around
// MFMA clusters (T5) and defer-max rescale skip (T13, THR=8; exact in fp32).
// ---------------------------------------------------------------------------
__global__ __launch_bounds__(256) void flash_attn_mfma(
        const ushort* __restrict__ qh, const ushort* __restrict__ kh,
        const ushort* __restrict__ vh,
        ushort* __restrict__ Oh, ushort* __restrict__ Ol)
{
    __shared__ __align__(16) ushort SMEM[13824];   // 27648B
    ushort* sk  = SMEM;            // [64][72]
    ushort* svt = SMEM + 4608;     // [64][72]
    ushort* pw0 = SMEM + 9216;     // 4 x [16][72]

    const int bid  = blockIdx.x;
    const int slot = bid >> 3;
    const int bh   = (bid & 7) * 8 + (slot >> 4);
    const int qt   = slot & 15;
    const int b    = bh >> 4;
    const int h    = bh & 15;
    const int qb   = qt * 64;

    const int t = threadIdx.x, lane = t & 63, w = t >> 6;
    const int l15 = lane & 15, g = lane >> 4;

    bf16x8_t qf[2];
    {
        size_t qrow = ((size_t)(b * NQ_) + qb + w * 16 + l15) * D_ + h * DH_;
        qf[0] = *(const bf16x8_t*)&qh[qrow + 0  + 8 * g];
        qf[1] = *(const bf16x8_t*)&qh[qrow + 32 + 8 * g];
    }

    f32x4_t acc[4];   // O^T[d = 16*dt + 4g + r][q = l15]
    #pragma unroll
    for (int dt = 0; dt < 4; ++dt) acc[dt] = (f32x4_t){0.f, 0.f, 0.f, 0.f};
    float m = -INFINITY, l = 0.0f;

    const int kkv = t >> 2;            // 0..63
    const int kds = (t & 3) * 16;      // 0,16,32,48
    const int vkv = t & 63;            // 0..63
    const int vds = (t >> 6) * 16;     // 0,16,32,48
    const size_t kvbase = (size_t)(b * NK_) * D_ + h * DH_;

    bf16x8_t kr0 = *(const bf16x8_t*)&kh[kvbase + (size_t)kkv * D_ + kds];
    bf16x8_t kr1 = *(const bf16x8_t*)&kh[kvbase + (size_t)kkv * D_ + kds + 8];
    bf16x8_t vr0 = *(const bf16x8_t*)&vh[kvbase + (size_t)vkv * D_ + vds];
    bf16x8_t vr1 = *(const bf16x8_t*)&vh[kvbase + (size_t)vkv * D_ + vds + 8];

    ushort* pw = pw0 + w * 1152;

    for (int kt = 0; kt < NK_; kt += 64) {
        __syncthreads();
        *(bf16x8_t*)&sk[kkv * 72 + kds]     = kr0;
        *(bf16x8_t*)&sk[kkv * 72 + kds + 8] = kr1;
        #pragma unroll
        for (int j = 0; j < 8; ++j) {
            svt[(vds + j)     * 72 + vkv] = (ushort)vr0[j];
            svt[(vds + 8 + j) * 72 + vkv] = (ushort)vr1[j];
        }
        __syncthreads();
        if (kt + 64 < NK_) {
            kr0 = *(const bf16x8_t*)&kh[kvbase + (size_t)(kt + 64 + kkv) * D_ + kds];
            kr1 = *(const bf16x8_t*)&kh[kvbase + (size_t)(kt + 64 + kkv) * D_ + kds + 8];
            vr0 = *(const bf16x8_t*)&vh[kvbase + (size_t)(kt + 64 + vkv) * D_ + vds];
            vr1 = *(const bf16x8_t*)&vh[kvbase + (size_t)(kt + 64 + vkv) * D_ + vds + 8];
        }

        // QK^T swapped: S^T[kv = 16*tq + 4g + r][q = l15]
        f32x4_t s[4];
        #pragma unroll
        for (int tq = 0; tq < 4; ++tq) s[tq] = (f32x4_t){0.f,0.f,0.f,0.f};
        __builtin_amdgcn_s_setprio(1);
        #pragma unroll
        for (int c = 0; c < 2; ++c)
            #pragma unroll
            for (int tq = 0; tq < 4; ++tq) {
                bf16x8_t kf = *(const bf16x8_t*)&sk[(l15 + 16 * tq) * 72 + 32 * c + 8 * g];
                s[tq] = __builtin_amdgcn_mfma_f32_16x16x32_bf16(kf, qf[c], s[tq], 0, 0, 0);
            }
        __builtin_amdgcn_s_setprio(0);

        // per-lane online softmax over 16 scores; defer-max (THR=8)
        float e[16];
        #pragma unroll
        for (int tq = 0; tq < 4; ++tq)
            #pragma unroll
            for (int r = 0; r < 4; ++r)
                e[4 * tq + r] = s[tq][r] * SCALE_;
        float tmax = e[0];
        #pragma unroll
        for (int i = 1; i < 16; ++i) tmax = fmaxf(tmax, e[i]);
        tmax = fmaxf(tmax, __shfl_xor(tmax, 16, 64));
        tmax = fmaxf(tmax, __shfl_xor(tmax, 32, 64));
        const bool defer = __all(tmax - m <= 8.0f);
        float mn = defer ? m : fmaxf(m, tmax);
        float p[16];
        float ps = 0.f;
        #pragma unroll
        for (int i = 0; i < 16; ++i) { p[i] = __expf(e[i] - mn); ps += p[i]; }
        ps += __shfl_xor(ps, 16, 64);
        ps += __shfl_xor(ps, 32, 64);
        if (defer) {
            l += ps;
        } else {
            float corr = __expf(m - mn);
            l = l * corr + ps;
            #pragma unroll
            for (int dt = 0; dt < 4; ++dt)
                #pragma unroll
                for (int r = 0; r < 4; ++r)
                    acc[dt][r] *= corr;
            m = mn;
        }

        // P -> per-wave LDS (packed b64); read back as PV B-frags
        #pragma unroll
        for (int tq = 0; tq < 4; ++tq) {
            ushort4 pk;
            pk.x = f2bf_rne(p[4 * tq + 0]); pk.y = f2bf_rne(p[4 * tq + 1]);
            pk.z = f2bf_rne(p[4 * tq + 2]); pk.w = f2bf_rne(p[4 * tq + 3]);
            *(ushort4*)&pw[l15 * 72 + 16 * tq + 4 * g] = pk;
        }
        bf16x8_t pa0 = *(const bf16x8_t*)&pw[l15 * 72 + 8 * g];        // kv 0..31
        bf16x8_t pa1 = *(const bf16x8_t*)&pw[l15 * 72 + 32 + 8 * g];   // kv 32..63

        // PV swapped: O^T[d][q] += V^T[d][kv] * P[q][kv]
        __builtin_amdgcn_s_setprio(1);
        #pragma unroll
        for (int dt = 0; dt < 4; ++dt) {
            bf16x8_t vf0 = *(const bf16x8_t*)&svt[(16 * dt + l15) * 72 + 8 * g];
            bf16x8_t vf1 = *(const bf16x8_t*)&svt[(16 * dt + l15) * 72 + 32 + 8 * g];
            acc[dt] = __builtin_amdgcn_mfma_f32_16x16x32_bf16(vf0, pa0, acc[dt], 0, 0, 0);
            acc[dt] = __builtin_amdgcn_mfma_f32_16x16x32_bf16(vf1, pa1, acc[dt], 0, 0, 0);
        }
        __builtin_amdgcn_s_setprio(0);
    }

    // epilogue: O^T -> O via per-wave LDS bounce, coalesced split-plane stores
    __syncthreads();
    float invl = 1.0f / l;
    float* Ew = (float*)SMEM + w * 1024;
    #pragma unroll
    for (int dt = 0; dt < 4; ++dt)
        #pragma unroll
        for (int r = 0; r < 4; ++r)
            Ew[(16 * dt + 4 * g + r) * 16 + l15] = acc[dt][r] * invl;
    const int ql = lane >> 2;
    const int dc = (lane & 3) * 16;
    float ov[16];
    #pragma unroll
    for (int j = 0; j < 16; ++j) ov[j] = Ew[(dc + j) * 16 + ql];
    bf16x8_t hv0, hv1, lv0, lv1;
    #pragma unroll
    for (int j = 0; j < 8; ++j) {
        ushort ha = f2bf_rne(ov[j]);
        ushort hb = f2bf_rne(ov[8 + j]);
        hv0[j] = (short)ha; lv0[j] = (short)f2bf_rne(ov[j] - bf2f(ha));
        hv1[j] = (short)hb; lv1[j] = (short)f2bf_rne(ov[8 + j] - bf2f(hb));
    }
    size_t orow = ((size_t)(b * NQ_) + qb + w * 16 + ql) * D_ + h * DH_ + dc;
    *(bf16x8_t*)&Oh[orow]     = hv0;
    *(bf16x8_t*)&Oh[orow + 8] = hv1;
    *(bf16x8_t*)&Ol[orow]     = lv0;
    *(bf16x8_t*)&Ol[orow + 8] = lv1;
}

// ---------------------------------------------------------------------------
// LN0: out-planes-only. vv = a0 + a1 + r (fp32); LN; write bf16 hi/lo planes.
// ---------------------------------------------------------------------------
__global__ __launch_bounds__(256) void add_ln_so(const float* __restrict__ a0,
        const float* __restrict__ a1, const float* __restrict__ r,
        const float* __restrict__ g, const float* __restrict__ be,
        ushort* __restrict__ oh, ushort* __restrict__ ol)
{
    const int row = blockIdx.x;
    const int t = threadIdx.x;
    float vals[4];
    float s1 = 0.0f, s2 = 0.0f;
    #pragma unroll
    for (int i = 0; i < 4; ++i) {
        int col = t + i * 256;
        size_t o = (size_t)row * D_ + col;
        float vv = a0[o] + a1[o] + r[o];
        vals[i] = vv;
        s1 += vv;
        s2 += vv * vv;
    }
    #pragma unroll
    for (int off = 32; off > 0; off >>= 1) {
        s1 += __shfl_down(s1, off, 64);
        s2 += __shfl_down(s2, off, 64);
    }
    __shared__ float p1[4], p2[4];
    const int wave = t >> 6;
    if ((t & 63) == 0) { p1[wave] = s1; p2[wave] = s2; }
    __syncthreads();
    s1 = p1[0] + p1[1] + p1[2] + p1[3];
    s2 = p2[0] + p2[1] + p2[2] + p2[3];
    const float mean = s1 * (1.0f / D_);
    const float var  = s2 * (1.0f / D_) - mean * mean;
    const float rstd = rsqrtf(var + LN_EPS_);
    #pragma unroll
    for (int i = 0; i < 4; ++i) {
        int col = t + i * 256;
        float v = (vals[i] - mean) * rstd * g[col] + be[col];
        ushort h = f2bf_rne(v);
        oh[(size_t)row * D_ + col] = h;
        ol[(size_t)row * D_ + col] = f2bf_rne(v - bf2f(h));
    }
}

// ---------------------------------------------------------------------------
// Final LN: residual from planes. vv = a0 + a1 + (rh + rl); write fp32.
// out may alias a1 (each thread reads its own elements before writing).
// ---------------------------------------------------------------------------
__global__ __launch_bounds__(256) void add_ln_pr(const float* __restrict__ a0,
        const float* __restrict__ a1,
        const ushort* __restrict__ rh, const ushort* __restrict__ rl,
        const float* __restrict__ g, const float* __restrict__ be,
        float* __restrict__ out)
{
    const int row = blockIdx.x;
    const int t = threadIdx.x;
    float vals[4];
    float s1 = 0.0f, s2 = 0.0f;
    #pragma unroll
    for (int i = 0; i < 4; ++i) {
        int col = t + i * 256;
        size_t o = (size_t)row * D_ + col;
        float rr = bf2f(rh[o]) + bf2f(rl[o]);
        float vv = a0[o] + a1[o] + rr;
        vals[i] = vv;
        s1 += vv;
        s2 += vv * vv;
    }
    #pragma unroll
    for (int off = 32; off > 0; off >>= 1) {
        s1 += __shfl_down(s1, off, 64);
        s2 += __shfl_down(s2, off, 64);
    }
    __shared__ float p1[4], p2[4];
    const int wave = t >> 6;
    if ((t & 63) == 0) { p1[wave] = s1; p2[wave] = s2; }
    __syncthreads();
    s1 = p1[0] + p1[1] + p1[2] + p1[3];
    s2 = p2[0] + p2[1] + p2[2] + p2[3];
    const float mean = s1 * (1.0f / D_);
    const float var  = s2 * (1.0f / D_) - mean * mean;
    const float rstd = rsqrtf(var + LN_EPS_);
    #pragma unroll
    for (int i = 0; i < 4; ++i) {
        int col = t + i * 256;
        out[(size_t)row * D_ + col] = (vals[i] - mean) * rstd * g[col] + be[col];
    }
}

// ---------------------------------------------------------------------------
// Workspace (MB offsets, 112MB):
//   Qh 0 Ql 8 Kh 16 Kl 24 | W splits 32..48 | qhp 48 khp 56 vhp 64
//   attn: aOh 72 aOl 80
//   Wo splitk: oprj0@16, oprj1@56
//   add_ln_so: Xh@32 Xl@40 (live to end)
//   W1h@16 W1l@24 ; FFN1 -> Hih@80(32MB) Hil@48(32MB)
//   W2h@16 W2l@24 ; FFN2 splitk: Y0@0 (bias), Y1 = d_out (scratch)
//   add_ln_pr(Y0, d_out, Xh, Xl) -> d_out
// ---------------------------------------------------------------------------
extern "C" void kernel_launch(void* const* d_in, const int* in_sizes, int n_in,
                              void* d_out, int out_size, void* d_ws, size_t ws_size,
                              hipStream_t stream)
{
    const float* Q   = (const float*)d_in[0];
    const float* K   = (const float*)d_in[1];
    const float* Wq  = (const float*)d_in[2];
    const float* bq  = (const float*)d_in[3];
    const float* Wk  = (const float*)d_in[4];
    const float* bk  = (const float*)d_in[5];
    const float* Wv  = (const float*)d_in[6];
    const float* bv  = (const float*)d_in[7];
    const float* Wo  = (const float*)d_in[8];
    const float* bo  = (const float*)d_in[9];
    const float* W1  = (const float*)d_in[10];
    const float* b1  = (const float*)d_in[11];
    const float* W2  = (const float*)d_in[12];
    const float* b2  = (const float*)d_in[13];
    const float* g0  = (const float*)d_in[14];
    const float* be0 = (const float*)d_in[15];
    const float* g1  = (const float*)d_in[16];
    const float* be1 = (const float*)d_in[17];

    unsigned char* Wb = (unsigned char*)d_ws;
    const size_t MBy = 1ull << 20;

    ushort* Qh   = (ushort*)(Wb +  0 * MBy);
    ushort* Ql   = (ushort*)(Wb +  8 * MBy);
    ushort* Kh   = (ushort*)(Wb + 16 * MBy);
    ushort* Kl   = (ushort*)(Wb + 24 * MBy);
    ushort* Wqh  = (ushort*)(Wb + 32 * MBy);
    ushort* Wql  = (ushort*)(Wb + 34 * MBy);
    ushort* Wkh  = (ushort*)(Wb + 36 * MBy);
    ushort* Wkl  = (ushort*)(Wb + 38 * MBy);
    ushort* Wvh  = (ushort*)(Wb + 40 * MBy);
    ushort* Wvl  = (ushort*)(Wb + 42 * MBy);
    ushort* Woh  = (ushort*)(Wb + 44 * MBy);
    ushort* Wol  = (ushort*)(Wb + 46 * MBy);
    ushort* qhp  = (ushort*)(Wb + 48 * MBy);
    ushort* khp  = (ushort*)(Wb + 56 * MBy);
    ushort* vhp  = (ushort*)(Wb + 64 * MBy);
    ushort* aOh  = (ushort*)(Wb + 72 * MBy);
    ushort* aOl  = (ushort*)(Wb + 80 * MBy);

    float*  oprj0 = (float*)(Wb + 16 * MBy);
    float*  oprj1 = (float*)(Wb + 56 * MBy);
    ushort* Xh    = (ushort*)(Wb + 32 * MBy);   // live to final LN
    ushort* Xl    = (ushort*)(Wb + 40 * MBy);
    ushort* W1h   = (ushort*)(Wb + 16 * MBy);
    ushort* W1l   = (ushort*)(Wb + 24 * MBy);
    ushort* Hih   = (ushort*)(Wb + 80 * MBy);   // 32MB: 80-112
    ushort* Hil   = (ushort*)(Wb + 48 * MBy);   // 32MB: 48-80
    ushort* W2h   = (ushort*)(Wb + 16 * MBy);
    ushort* W2l   = (ushort*)(Wb + 24 * MBy);
    float*  Y0    = (float*)(Wb +  0 * MBy);    // freed (ex-Qh/Ql region)
    float*  Y1    = (float*)d_out;              // scratch until final LN

    const int M = B_ * NQ_;
    const int n4act = M * D_ / 4;
    dim3 blk(256);
    dim3 gQKV(D_ / 128, M / 128, 3);
    dim3 gSK(D_ / 128, M / 128, 2);

    Rows2 r2;
    r2.src[0] = Q; r2.hi[0] = Qh; r2.lo[0] = Ql;
    r2.src[1] = K; r2.hi[1] = Kh; r2.lo[1] = Kl;
    split_rows2<<<dim3(n4act / 256, 1, 2), blk, 0, stream>>>(r2, n4act);

    Tr4 t4;
    t4.w[0] = Wq; t4.th[0] = Wqh; t4.tl[0] = Wql;
    t4.w[1] = Wk; t4.th[1] = Wkh; t4.tl[1] = Wkl;
    t4.w[2] = Wv; t4.th[2] = Wvh; t4.tl[2] = Wvl;
    t4.w[3] = Wo; t4.th[3] = Woh; t4.tl[3] = Wol;
    split_tr4<<<dim3(D_/32, D_/32, 4), blk, 0, stream>>>(t4);

    QkvArgs qa;
    qa.Ah[0] = Qh;  qa.Al[0] = Ql;  qa.Bh[0] = Wqh; qa.Bl[0] = Wql; qa.bias[0] = bq; qa.Co[0] = qhp;
    qa.Ah[1] = Kh;  qa.Al[1] = Kl;  qa.Bh[1] = Wkh; qa.Bl[1] = Wkl; qa.bias[1] = bk; qa.Co[1] = khp;
    qa.Ah[2] = Kh;  qa.Al[2] = Kl;  qa.Bh[2] = Wvh; qa.Bl[2] = Wvl; qa.bias[2] = bv; qa.Co[2] = vhp;
    gemm_qkv<<<gQKV, blk, 0, stream>>>(qa, M, D_, D_);

    flash_attn_mfma<<<dim3(1024), blk, 0, stream>>>(qhp, khp, vhp, aOh, aOl);

    // output projection, split-K=2 (2 blocks/CU) + LN0 -> planes only
    gemm_splitk2<<<gSK, blk, 0, stream>>>(aOh, aOl, Woh, Wol, bo, oprj0, oprj1, M, D_, D_);
    add_ln_so<<<M, blk, 0, stream>>>(oprj0, oprj1, Q, g0, be0, Xh, Xl);

    split_tr<<<dim3(DFF_/32, D_/32), blk, 0, stream>>>(W1, W1h, W1l, D_, DFF_);
    gemm_ffn1_256<<<dim3(DFF_/256, M/256), dim3(512), 0, stream>>>(
        Xh, Xl, W1h, W1l, b1, Hih, Hil, M, DFF_, D_);
    split_tr<<<dim3(D_/32, DFF_/32), blk, 0, stream>>>(W2, W2h, W2l, DFF_, D_);

    // FFN2: split-K=2 (proven r13 config); Y0 in freed region, Y1 = d_out
    gemm_splitk2<<<gSK, blk, 0, stream>>>(Hih, Hil, W2h, W2l, b2, Y0, Y1, M, D_, DFF_);
    add_ln_pr<<<M, blk, 0, stream>>>(Y0, Y1, Xh, Xl, g1, be1, (float*)d_out);
}

// Round 17
// 374.447 us; speedup vs baseline: 1.0758x; 1.0198x over previous
//
#include <hip/hip_runtime.h>
#include <math.h>

#define B_   4
#define NQ_  1024
#define NK_  1024
#define D_   1024
#define H_   16
#define DH_  64
#define DFF_ 4096
#define SCALE_ (1.0f/32.0f)   // 1/sqrt(D)
#define LN_EPS_ 1e-5f

typedef __attribute__((ext_vector_type(8))) short bf16x8_t;  // 8 bf16 = 4 VGPR
typedef __attribute__((ext_vector_type(4))) float f32x4_t;

__device__ __forceinline__ ushort f2bf_rne(float x) {
    unsigned u = __float_as_uint(x);
    unsigned r = (u + 0x7FFFu + ((u >> 16) & 1u)) >> 16;
    return (ushort)r;
}
__device__ __forceinline__ float bf2f(ushort h) {
    return __uint_as_float(((unsigned)h) << 16);
}

// async global->LDS, 16B per lane. LDS dest = wave-uniform base + lane*16.
__device__ __forceinline__ void gl_lds16(const ushort* g, ushort* l) {
    __builtin_amdgcn_global_load_lds(
        (const __attribute__((address_space(1))) unsigned int*)g,
        (__attribute__((address_space(3))) unsigned int*)l, 16, 0, 0);
}

// ---------------------------------------------------------------------------
// fp32 -> (hi,lo) bf16 planes; fused 2-tensor variant (z picks tensor).
// ---------------------------------------------------------------------------
struct Rows2 { const float* src[2]; ushort* hi[2]; ushort* lo[2]; };

__global__ __launch_bounds__(256) void split_rows2(Rows2 a, int n4)
{
    int i = blockIdx.x * 256 + threadIdx.x;
    if (i >= n4) return;
    const int z = blockIdx.z;
    float4 v = ((const float4*)a.src[z])[i];
    ushort4 h, l;
    h.x = f2bf_rne(v.x); l.x = f2bf_rne(v.x - bf2f(h.x));
    h.y = f2bf_rne(v.y); l.y = f2bf_rne(v.y - bf2f(h.y));
    h.z = f2bf_rne(v.z); l.z = f2bf_rne(v.z - bf2f(h.z));
    h.w = f2bf_rne(v.w); l.w = f2bf_rne(v.w - bf2f(h.w));
    ((ushort4*)a.hi[z])[i] = h;
    ((ushort4*)a.lo[z])[i] = l;
}

// ---------------------------------------------------------------------------
// Weight split + transpose: W[K][N] fp32 -> planes Wt[N][K] bf16.
// ---------------------------------------------------------------------------
__device__ __forceinline__ void split_tr_body(const float* __restrict__ Wsrc,
        ushort* __restrict__ th, ushort* __restrict__ tl, int K, int N)
{
    __shared__ float tile[32][33];
    const int nb = blockIdx.x * 32, kb = blockIdx.y * 32;
    const int t = threadIdx.x;
    {
        int r = t >> 3, c4 = (t & 7) * 4;
        float4 v = *(const float4*)&Wsrc[(size_t)(kb + r) * N + nb + c4];
        tile[r][c4 + 0] = v.x; tile[r][c4 + 1] = v.y;
        tile[r][c4 + 2] = v.z; tile[r][c4 + 3] = v.w;
    }
    __syncthreads();
    {
        int n = t >> 3, k4 = (t & 7) * 4;
        float a0 = tile[k4 + 0][n], a1 = tile[k4 + 1][n];
        float a2 = tile[k4 + 2][n], a3 = tile[k4 + 3][n];
        ushort4 h, l;
        h.x = f2bf_rne(a0); l.x = f2bf_rne(a0 - bf2f(h.x));
        h.y = f2bf_rne(a1); l.y = f2bf_rne(a1 - bf2f(h.y));
        h.z = f2bf_rne(a2); l.z = f2bf_rne(a2 - bf2f(h.z));
        h.w = f2bf_rne(a3); l.w = f2bf_rne(a3 - bf2f(h.w));
        size_t o = (size_t)(nb + n) * K + kb + k4;
        *(ushort4*)&th[o] = h;
        *(ushort4*)&tl[o] = l;
    }
}

__global__ __launch_bounds__(256) void split_tr(const float* __restrict__ Wsrc,
        ushort* __restrict__ th, ushort* __restrict__ tl, int K, int N)
{
    split_tr_body(Wsrc, th, tl, K, N);
}

struct Tr4 { const float* w[4]; ushort* th[4]; ushort* tl[4]; };

__global__ __launch_bounds__(256) void split_tr4(Tr4 a)
{
    const int z = blockIdx.z;
    split_tr_body(a.w[z], a.th[z], a.tl[z], D_, D_);
}

// bijective XCD-chunked swizzle (nwg % 8 == 0 for all our grids)
__device__ __forceinline__ void swz_block(int& brow, int& bcol, int tile) {
    const int nx  = gridDim.x;
    const int lin = blockIdx.y * nx + blockIdx.x;
    const int cpx = (nx * gridDim.y) >> 3;
    const int swz = (lin & 7) * cpx + (lin >> 3);
    brow = (swz / nx) * tile;
    bcol = (swz % nx) * tile;
}

// ---------------------------------------------------------------------------
// MFMA GEMM body (r17): 2-phase counted-vmcnt ring. 128^2, 4 waves.
// Phase A: {read Ah,Bh; issue G0=[Ah,Bh](t+1); vmcnt(4); bar; 16 MFMA hh}
// Phase B: {read Bl,Al; issue G1=[Bl,Al](t+1); vmcnt(4); bar; 32 MFMA hl,lh}
// Per-wave 4 issues/group -> steady wait vmcnt(4); last tile 0/skip.
// Per-element accumulate order unchanged (hh,hl,lh) -> bit-identical.
// ---------------------------------------------------------------------------
template<bool RELU, int OMODE>
__device__ __forceinline__ void gemm_body(
        const ushort* __restrict__ Ah, const ushort* __restrict__ Al,
        const ushort* __restrict__ Bh, const ushort* __restrict__ Bl,
        const float* __restrict__ bias,
        float* __restrict__ C, ushort* __restrict__ Ch, ushort* __restrict__ Cl,
        int M, int N, int Kd, int Klen, int brow, int bcol)
{
    __shared__ __align__(16) ushort S[2][4][128 * 32];   // 64KB dbuf

    const int t    = threadIdx.x;
    const int lane = t & 63;
    const int w    = t >> 6;
    const int wr   = (w >> 1) * 64;
    const int wc   = (w & 1) * 64;
    const int fr   = lane & 15;
    const int g    = lane >> 4;
    const int sS   = ((g ^ ((fr >> 1) & 3)) << 3);
    const int cl   = lane & 15;
    const int rq   = (lane >> 4) * 4;

    float bpre[4];
    #pragma unroll
    for (int j = 0; j < 4; ++j)
        bpre[j] = bias ? bias[bcol + wc + j * 16 + cl] : 0.f;

    f32x4_t acc[4][4];
    #pragma unroll
    for (int i = 0; i < 4; ++i)
        #pragma unroll
        for (int j = 0; j < 4; ++j)
            acc[i][j] = (f32x4_t){0.f, 0.f, 0.f, 0.f};

    const int lrow  = lane >> 2;
    const int lslot = ((lane & 3) ^ ((lane >> 3) & 3)) << 3;
    const int c0    = w * 2;

    auto issue2 = [&](const ushort* gpp, int rb, int pl, int buf, int k0) {
        #pragma unroll
        for (int ii = 0; ii < 2; ++ii) {
            int c = c0 + ii;
            gl_lds16(gpp + (size_t)(rb + c * 16 + lrow) * Kd + k0 + lslot,
                     &S[buf][pl][c * 512]);
        }
    };

    bf16x8_t ahf[4], bhf[4], blf[4], alf[4];

    // prologue: G0=[Ah,Bh], G1=[Bl,Al] of tile 0
    issue2(Ah, brow, 0, 0, 0);
    issue2(Bh, bcol, 2, 0, 0);
    issue2(Bl, bcol, 3, 0, 0);
    issue2(Al, brow, 1, 0, 0);
    asm volatile("s_waitcnt vmcnt(4)" ::: "memory");   // G0(0) done
    __builtin_amdgcn_s_barrier();

    const int NT = Klen >> 5;
    for (int tt = 0; tt < NT; ++tt) {
        const int cur = tt & 1, nxt = cur ^ 1;
        const int kn  = (tt + 1) << 5;
        const bool more = (tt + 1 < NT);

        // ---- phase A: hh — read Ah,Bh(cur); issue G0(t+1); confirm G1(t)
        #pragma unroll
        for (int i = 0; i < 4; ++i)
            ahf[i] = *(const bf16x8_t*)&S[cur][0][(wr + i * 16 + fr) * 32 + sS];
        #pragma unroll
        for (int j = 0; j < 4; ++j)
            bhf[j] = *(const bf16x8_t*)&S[cur][2][(wc + j * 16 + fr) * 32 + sS];
        if (more) {
            issue2(Ah, brow, 0, nxt, kn);
            issue2(Bh, bcol, 2, nxt, kn);
            asm volatile("s_waitcnt vmcnt(4)" ::: "memory");
        } else {
            asm volatile("s_waitcnt vmcnt(0)" ::: "memory");
        }
        __builtin_amdgcn_s_barrier();
        asm volatile("s_waitcnt lgkmcnt(0)" ::: "memory");
        __builtin_amdgcn_sched_barrier(0);
        __builtin_amdgcn_s_setprio(1);
        #pragma unroll
        for (int i = 0; i < 4; ++i)
            #pragma unroll
            for (int j = 0; j < 4; ++j)
                acc[i][j] = __builtin_amdgcn_mfma_f32_16x16x32_bf16(ahf[i], bhf[j], acc[i][j], 0, 0, 0);
        __builtin_amdgcn_s_setprio(0);

        // ---- phase B: hl+lh — read Bl,Al(cur); issue G1(t+1); confirm G0(t+1)
        #pragma unroll
        for (int j = 0; j < 4; ++j)
            blf[j] = *(const bf16x8_t*)&S[cur][3][(wc + j * 16 + fr) * 32 + sS];
        #pragma unroll
        for (int i = 0; i < 4; ++i)
            alf[i] = *(const bf16x8_t*)&S[cur][1][(wr + i * 16 + fr) * 32 + sS];
        if (more) {
            issue2(Bl, bcol, 3, nxt, kn);
            issue2(Al, brow, 1, nxt, kn);
            asm volatile("s_waitcnt vmcnt(4)" ::: "memory");
        }
        __builtin_amdgcn_s_barrier();
        asm volatile("s_waitcnt lgkmcnt(0)" ::: "memory");
        __builtin_amdgcn_sched_barrier(0);
        __builtin_amdgcn_s_setprio(1);
        #pragma unroll
        for (int i = 0; i < 4; ++i)
            #pragma unroll
            for (int j = 0; j < 4; ++j)
                acc[i][j] = __builtin_amdgcn_mfma_f32_16x16x32_bf16(ahf[i], blf[j], acc[i][j], 0, 0, 0);
        #pragma unroll
        for (int i = 0; i < 4; ++i)
            #pragma unroll
            for (int j = 0; j < 4; ++j)
                acc[i][j] = __builtin_amdgcn_mfma_f32_16x16x32_bf16(alf[i], bhf[j], acc[i][j], 0, 0, 0);
        __builtin_amdgcn_s_setprio(0);
    }

    if (OMODE == 0) {
        #pragma unroll
        for (int j = 0; j < 4; ++j) {
            int col = bcol + wc + j * 16 + cl;
            #pragma unroll
            for (int i = 0; i < 4; ++i)
                #pragma unroll
                for (int r = 0; r < 4; ++r) {
                    int row = brow + wr + i * 16 + rq + r;
                    float v = acc[i][j][r] + bpre[j];
                    if (RELU) v = fmaxf(v, 0.f);
                    C[(size_t)row * N + col] = v;
                }
        }
    } else {
        __syncthreads();   // all waves done reading S (no trailing loop barrier)
        float* E = (float*)&S[0][0][0] + w * 4096;   // 16KB per wave
        #pragma unroll
        for (int j = 0; j < 4; ++j) {
            #pragma unroll
            for (int i = 0; i < 4; ++i)
                #pragma unroll
                for (int r = 0; r < 4; ++r) {
                    float v = acc[i][j][r] + bpre[j];
                    if (RELU) v = fmaxf(v, 0.f);
                    E[(i * 16 + rq + r) * 64 + j * 16 + cl] = v;
                }
        }
        __syncthreads();
        const int rr8 = lane >> 3;
        const int c8  = (lane & 7) * 8;
        #pragma unroll
        for (int p = 0; p < 8; ++p) {
            int rl = p * 8 + rr8;
            float4 va = *(float4*)&E[rl * 64 + c8];
            float4 vb = *(float4*)&E[rl * 64 + c8 + 4];
            float v[8] = {va.x, va.y, va.z, va.w, vb.x, vb.y, vb.z, vb.w};
            bf16x8_t hv, lv;
            #pragma unroll
            for (int q = 0; q < 8; ++q) {
                ushort hh = f2bf_rne(v[q]);
                hv[q] = (short)hh;
                lv[q] = (short)f2bf_rne(v[q] - bf2f(hh));
            }
            size_t o = (size_t)(brow + wr + rl) * N + (bcol + wc + c8);
            *(bf16x8_t*)&Ch[o] = hv;
            if (OMODE == 1) *(bf16x8_t*)&Cl[o] = lv;
        }
    }
}

// split-K=2 (validated r11/r13): grid.z picks K-window; z=0 carries bias.
__global__ __launch_bounds__(256) void gemm_splitk2(
        const ushort* __restrict__ Ah, const ushort* __restrict__ Al,
        const ushort* __restrict__ Bh, const ushort* __restrict__ Bl,
        const float* __restrict__ bias,
        float* __restrict__ C0, float* __restrict__ C1,
        int M, int N, int Kd)
{
    int brow, bcol;
    swz_block(brow, bcol, 128);
    const int z = blockIdx.z;
    const int Kh2 = Kd >> 1;
    const int ko  = z * Kh2;
    gemm_body<false, 0>(Ah + ko, Al + ko, Bh + ko, Bl + ko,
                        z == 0 ? bias : nullptr,
                        z == 0 ? C0 : C1, nullptr, nullptr,
                        M, N, Kd, Kh2, brow, bcol);
}

// q/k/v projections fused into one dispatch (grid.z = 3 -> 768 blocks)
struct QkvArgs {
    const ushort* Ah[3]; const ushort* Al[3];
    const ushort* Bh[3]; const ushort* Bl[3];
    const float*  bias[3];
    ushort*       Co[3];
};

__global__ __launch_bounds__(256) void gemm_qkv(QkvArgs qa, int M, int N, int Kd)
{
    int brow, bcol;
    swz_block(brow, bcol, 128);
    const int z = blockIdx.z;
    gemm_body<false, 2>(qa.Ah[z], qa.Al[z], qa.Bh[z], qa.Bl[z], qa.bias[z],
                        nullptr, qa.Co[z], nullptr, M, N, Kd, Kd, brow, bcol);
}

// ---------------------------------------------------------------------------
// FFN1 (r17): 256^2 tile, 8 waves, 2-phase ring (phase B = 64 MFMA).
// ---------------------------------------------------------------------------
__global__ __launch_bounds__(512) void gemm_ffn1_256(
        const ushort* __restrict__ Ah, const ushort* __restrict__ Al,
        const ushort* __restrict__ Bh, const ushort* __restrict__ Bl,
        const float* __restrict__ bias,
        ushort* __restrict__ Ch, ushort* __restrict__ Cl,
        int M, int N, int Kd)
{
    __shared__ __align__(16) ushort S[2][4][256 * 32];   // 128KB

    const int t    = threadIdx.x;
    const int lane = t & 63;
    const int w    = t >> 6;
    const int wr   = (w >> 2) * 128;
    const int wc   = (w & 3) * 64;
    const int fr   = lane & 15;
    const int g    = lane >> 4;
    const int sS   = ((g ^ ((fr >> 1) & 3)) << 3);
    const int cl   = lane & 15;
    const int rq   = (lane >> 4) * 4;

    int brow, bcol;
    swz_block(brow, bcol, 256);

    float bpre[4];
    #pragma unroll
    for (int j = 0; j < 4; ++j) bpre[j] = bias[bcol + wc + j * 16 + cl];

    f32x4_t acc[8][4];
    #pragma unroll
    for (int i = 0; i < 8; ++i)
        #pragma unroll
        for (int j = 0; j < 4; ++j)
            acc[i][j] = (f32x4_t){0.f, 0.f, 0.f, 0.f};

    const int lrow  = lane >> 2;
    const int lslot = ((lane & 3) ^ ((lane >> 3) & 3)) << 3;
    const int c0    = w * 2;

    auto issue2 = [&](const ushort* gpp, int rb, int pl, int buf, int k0) {
        #pragma unroll
        for (int ii = 0; ii < 2; ++ii) {
            int c = c0 + ii;
            gl_lds16(gpp + (size_t)(rb + c * 16 + lrow) * Kd + k0 + lslot,
                     &S[buf][pl][c * 512]);
        }
    };

    bf16x8_t ahf[8], bhf[4], blf[4], alf[8];

    issue2(Ah, brow, 0, 0, 0);
    issue2(Bh, bcol, 2, 0, 0);
    issue2(Bl, bcol, 3, 0, 0);
    issue2(Al, brow, 1, 0, 0);
    asm volatile("s_waitcnt vmcnt(4)" ::: "memory");
    __builtin_amdgcn_s_barrier();

    const int NT = Kd >> 5;
    for (int tt = 0; tt < NT; ++tt) {
        const int cur = tt & 1, nxt = cur ^ 1;
        const int kn  = (tt + 1) << 5;
        const bool more = (tt + 1 < NT);

        // phase A: hh
        #pragma unroll
        for (int i = 0; i < 8; ++i)
            ahf[i] = *(const bf16x8_t*)&S[cur][0][(wr + i * 16 + fr) * 32 + sS];
        #pragma unroll
        for (int j = 0; j < 4; ++j)
            bhf[j] = *(const bf16x8_t*)&S[cur][2][(wc + j * 16 + fr) * 32 + sS];
        if (more) {
            issue2(Ah, brow, 0, nxt, kn);
            issue2(Bh, bcol, 2, nxt, kn);
            asm volatile("s_waitcnt vmcnt(4)" ::: "memory");
        } else {
            asm volatile("s_waitcnt vmcnt(0)" ::: "memory");
        }
        __builtin_amdgcn_s_barrier();
        asm volatile("s_waitcnt lgkmcnt(0)" ::: "memory");
        __builtin_amdgcn_sched_barrier(0);
        __builtin_amdgcn_s_setprio(1);
        #pragma unroll
        for (int i = 0; i < 8; ++i)
            #pragma unroll
            for (int j = 0; j < 4; ++j)
                acc[i][j] = __builtin_amdgcn_mfma_f32_16x16x32_bf16(ahf[i], bhf[j], acc[i][j], 0, 0, 0);
        __builtin_amdgcn_s_setprio(0);

        // phase B: hl + lh
        #pragma unroll
        for (int j = 0; j < 4; ++j)
            blf[j] = *(const bf16x8_t*)&S[cur][3][(wc + j * 16 + fr) * 32 + sS];
        #pragma unroll
        for (int i = 0; i < 8; ++i)
            alf[i] = *(const bf16x8_t*)&S[cur][1][(wr + i * 16 + fr) * 32 + sS];
        if (more) {
            issue2(Bl, bcol, 3, nxt, kn);
            issue2(Al, brow, 1, nxt, kn);
            asm volatile("s_waitcnt vmcnt(4)" ::: "memory");
        }
        __builtin_amdgcn_s_barrier();
        asm volatile("s_waitcnt lgkmcnt(0)" ::: "memory");
        __builtin_amdgcn_sched_barrier(0);
        __builtin_amdgcn_s_setprio(1);
        #pragma unroll
        for (int i = 0; i < 8; ++i)
            #pragma unroll
            for (int j = 0; j < 4; ++j)
                acc[i][j] = __builtin_amdgcn_mfma_f32_16x16x32_bf16(ahf[i], blf[j], acc[i][j], 0, 0, 0);
        #pragma unroll
        for (int i = 0; i < 8; ++i)
            #pragma unroll
            for (int j = 0; j < 4; ++j)
                acc[i][j] = __builtin_amdgcn_mfma_f32_16x16x32_bf16(alf[i], bhf[j], acc[i][j], 0, 0, 0);
        __builtin_amdgcn_s_setprio(0);
    }

    __syncthreads();
    float* E = (float*)&S[0][0][0] + w * 4096;
    const int rr8 = lane >> 3;
    const int c8  = (lane & 7) * 8;
    #pragma unroll
    for (int pass = 0; pass < 2; ++pass) {
        #pragma unroll
        for (int i = 0; i < 4; ++i) {
            #pragma unroll
            for (int j = 0; j < 4; ++j)
                #pragma unroll
                for (int r = 0; r < 4; ++r) {
                    float v = fmaxf(acc[pass * 4 + i][j][r] + bpre[j], 0.f);
                    E[(i * 16 + rq + r) * 64 + j * 16 + cl] = v;
                }
        }
        #pragma unroll
        for (int p = 0; p < 8; ++p) {
            int rl = p * 8 + rr8;
            float4 va = *(float4*)&E[rl * 64 + c8];
            float4 vb = *(float4*)&E[rl * 64 + c8 + 4];
            float v[8] = {va.x, va.y, va.z, va.w, vb.x, vb.y, vb.z, vb.w};
            bf16x8_t hv, lv;
            #pragma unroll
            for (int q = 0; q < 8; ++q) {
                ushort hh = f2bf_rne(v[q]);
                hv[q] = (short)hh;
                lv[q] = (short)f2bf_rne(v[q] - bf2f(hh));
            }
            size_t o = (size_t)(brow + wr + pass * 64 + rl) * N + (bcol + wc + c8);
            *(bf16x8_t*)&Ch[o] = hv;
            *(bf16x8_t*)&Cl[o] = lv;
        }
    }
}

// ---------------------------------------------------------------------------
// MFMA flash attention (r16-validated): KVBLK=64, swapped operands, setprio,
// defer-max THR=8, T14 reg prefetch, coalesced transposed epilogue.
// ---------------------------------------------------------------------------
__global__ __launch_bounds__(256) void flash_attn_mfma(
        const ushort* __restrict__ qh, const ushort* __restrict__ kh,
        const ushort* __restrict__ vh,
        ushort* __restrict__ Oh, ushort* __restrict__ Ol)
{
    __shared__ __align__(16) ushort SMEM[13824];   // 27648B
    ushort* sk  = SMEM;            // [64][72]
    ushort* svt = SMEM + 4608;     // [64][72]
    ushort* pw0 = SMEM + 9216;     // 4 x [16][72]

    const int bid  = blockIdx.x;
    const int slot = bid >> 3;
    const int bh   = (bid & 7) * 8 + (slot >> 4);
    const int qt   = slot & 15;
    const int b    = bh >> 4;
    const int h    = bh & 15;
    const int qb   = qt * 64;

    const int t = threadIdx.x, lane = t & 63, w = t >> 6;
    const int l15 = lane & 15, g = lane >> 4;

    bf16x8_t qf[2];
    {
        size_t qrow = ((size_t)(b * NQ_) + qb + w * 16 + l15) * D_ + h * DH_;
        qf[0] = *(const bf16x8_t*)&qh[qrow + 0  + 8 * g];
        qf[1] = *(const bf16x8_t*)&qh[qrow + 32 + 8 * g];
    }

    f32x4_t acc[4];   // O^T[d = 16*dt + 4g + r][q = l15]
    #pragma unroll
    for (int dt = 0; dt < 4; ++dt) acc[dt] = (f32x4_t){0.f, 0.f, 0.f, 0.f};
    float m = -INFINITY, l = 0.0f;

    const int kkv = t >> 2;            // 0..63
    const int kds = (t & 3) * 16;      // 0,16,32,48
    const int vkv = t & 63;            // 0..63
    const int vds = (t >> 6) * 16;     // 0,16,32,48
    const size_t kvbase = (size_t)(b * NK_) * D_ + h * DH_;

    bf16x8_t kr0 = *(const bf16x8_t*)&kh[kvbase + (size_t)kkv * D_ + kds];
    bf16x8_t kr1 = *(const bf16x8_t*)&kh[kvbase + (size_t)kkv * D_ + kds + 8];
    bf16x8_t vr0 = *(const bf16x8_t*)&vh[kvbase + (size_t)vkv * D_ + vds];
    bf16x8_t vr1 = *(const bf16x8_t*)&vh[kvbase + (size_t)vkv * D_ + vds + 8];

    ushort* pw = pw0 + w * 1152;

    for (int kt = 0; kt < NK_; kt += 64) {
        __syncthreads();
        *(bf16x8_t*)&sk[kkv * 72 + kds]     = kr0;
        *(bf16x8_t*)&sk[kkv * 72 + kds + 8] = kr1;
        #pragma unroll
        for (int j = 0; j < 8; ++j) {
            svt[(vds + j)     * 72 + vkv] = (ushort)vr0[j];
            svt[(vds + 8 + j) * 72 + vkv] = (ushort)vr1[j];
        }
        __syncthreads();
        if (kt + 64 < NK_) {
            kr0 = *(const bf16x8_t*)&kh[kvbase + (size_t)(kt + 64 + kkv) * D_ + kds];
            kr1 = *(const bf16x8_t*)&kh[kvbase + (size_t)(kt + 64 + kkv) * D_ + kds + 8];
            vr0 = *(const bf16x8_t*)&vh[kvbase + (size_t)(kt + 64 + vkv) * D_ + vds];
            vr1 = *(const bf16x8_t*)&vh[kvbase + (size_t)(kt + 64 + vkv) * D_ + vds + 8];
        }

        // QK^T swapped: S^T[kv = 16*tq + 4g + r][q = l15]
        f32x4_t s[4];
        #pragma unroll
        for (int tq = 0; tq < 4; ++tq) s[tq] = (f32x4_t){0.f,0.f,0.f,0.f};
        __builtin_amdgcn_s_setprio(1);
        #pragma unroll
        for (int c = 0; c < 2; ++c)
            #pragma unroll
            for (int tq = 0; tq < 4; ++tq) {
                bf16x8_t kf = *(const bf16x8_t*)&sk[(l15 + 16 * tq) * 72 + 32 * c + 8 * g];
                s[tq] = __builtin_amdgcn_mfma_f32_16x16x32_bf16(kf, qf[c], s[tq], 0, 0, 0);
            }
        __builtin_amdgcn_s_setprio(0);

        // per-lane online softmax over 16 scores; defer-max (THR=8)
        float e[16];
        #pragma unroll
        for (int tq = 0; tq < 4; ++tq)
            #pragma unroll
            for (int r = 0; r < 4; ++r)
                e[4 * tq + r] = s[tq][r] * SCALE_;
        float tmax = e[0];
        #pragma unroll
        for (int i = 1; i < 16; ++i) tmax = fmaxf(tmax, e[i]);
        tmax = fmaxf(tmax, __shfl_xor(tmax, 16, 64));
        tmax = fmaxf(tmax, __shfl_xor(tmax, 32, 64));
        const bool defer = __all(tmax - m <= 8.0f);
        float mn = defer ? m : fmaxf(m, tmax);
        float p[16];
        float ps = 0.f;
        #pragma unroll
        for (int i = 0; i < 16; ++i) { p[i] = __expf(e[i] - mn); ps += p[i]; }
        ps += __shfl_xor(ps, 16, 64);
        ps += __shfl_xor(ps, 32, 64);
        if (defer) {
            l += ps;
        } else {
            float corr = __expf(m - mn);
            l = l * corr + ps;
            #pragma unroll
            for (int dt = 0; dt < 4; ++dt)
                #pragma unroll
                for (int r = 0; r < 4; ++r)
                    acc[dt][r] *= corr;
            m = mn;
        }

        // P -> per-wave LDS (packed b64); read back as PV B-frags
        #pragma unroll
        for (int tq = 0; tq < 4; ++tq) {
            ushort4 pk;
            pk.x = f2bf_rne(p[4 * tq + 0]); pk.y = f2bf_rne(p[4 * tq + 1]);
            pk.z = f2bf_rne(p[4 * tq + 2]); pk.w = f2bf_rne(p[4 * tq + 3]);
            *(ushort4*)&pw[l15 * 72 + 16 * tq + 4 * g] = pk;
        }
        bf16x8_t pa0 = *(const bf16x8_t*)&pw[l15 * 72 + 8 * g];        // kv 0..31
        bf16x8_t pa1 = *(const bf16x8_t*)&pw[l15 * 72 + 32 + 8 * g];   // kv 32..63

        // PV swapped: O^T[d][q] += V^T[d][kv] * P[q][kv]
        __builtin_amdgcn_s_setprio(1);
        #pragma unroll
        for (int dt = 0; dt < 4; ++dt) {
            bf16x8_t vf0 = *(const bf16x8_t*)&svt[(16 * dt + l15) * 72 + 8 * g];
            bf16x8_t vf1 = *(const bf16x8_t*)&svt[(16 * dt + l15) * 72 + 32 + 8 * g];
            acc[dt] = __builtin_amdgcn_mfma_f32_16x16x32_bf16(vf0, pa0, acc[dt], 0, 0, 0);
            acc[dt] = __builtin_amdgcn_mfma_f32_16x16x32_bf16(vf1, pa1, acc[dt], 0, 0, 0);
        }
        __builtin_amdgcn_s_setprio(0);
    }

    // epilogue: O^T -> O via per-wave LDS bounce, coalesced split-plane stores
    __syncthreads();
    float invl = 1.0f / l;
    float* Ew = (float*)SMEM + w * 1024;
    #pragma unroll
    for (int dt = 0; dt < 4; ++dt)
        #pragma unroll
        for (int r = 0; r < 4; ++r)
            Ew[(16 * dt + 4 * g + r) * 16 + l15] = acc[dt][r] * invl;
    const int ql = lane >> 2;
    const int dc = (lane & 3) * 16;
    float ov[16];
    #pragma unroll
    for (int j = 0; j < 16; ++j) ov[j] = Ew[(dc + j) * 16 + ql];
    bf16x8_t hv0, hv1, lv0, lv1;
    #pragma unroll
    for (int j = 0; j < 8; ++j) {
        ushort ha = f2bf_rne(ov[j]);
        ushort hb = f2bf_rne(ov[8 + j]);
        hv0[j] = (short)ha; lv0[j] = (short)f2bf_rne(ov[j] - bf2f(ha));
        hv1[j] = (short)hb; lv1[j] = (short)f2bf_rne(ov[8 + j] - bf2f(hb));
    }
    size_t orow = ((size_t)(b * NQ_) + qb + w * 16 + ql) * D_ + h * DH_ + dc;
    *(bf16x8_t*)&Oh[orow]     = hv0;
    *(bf16x8_t*)&Oh[orow + 8] = hv1;
    *(bf16x8_t*)&Ol[orow]     = lv0;
    *(bf16x8_t*)&Ol[orow + 8] = lv1;
}

// ---------------------------------------------------------------------------
// LN0: out-planes-only. vv = a0 + a1 + r (fp32); LN; write bf16 hi/lo planes.
// ---------------------------------------------------------------------------
__global__ __launch_bounds__(256) void add_ln_so(const float* __restrict__ a0,
        const float* __restrict__ a1, const float* __restrict__ r,
        const float* __restrict__ g, const float* __restrict__ be,
        ushort* __restrict__ oh, ushort* __restrict__ ol)
{
    const int row = blockIdx.x;
    const int t = threadIdx.x;
    float vals[4];
    float s1 = 0.0f, s2 = 0.0f;
    #pragma unroll
    for (int i = 0; i < 4; ++i) {
        int col = t + i * 256;
        size_t o = (size_t)row * D_ + col;
        float vv = a0[o] + a1[o] + r[o];
        vals[i] = vv;
        s1 += vv;
        s2 += vv * vv;
    }
    #pragma unroll
    for (int off = 32; off > 0; off >>= 1) {
        s1 += __shfl_down(s1, off, 64);
        s2 += __shfl_down(s2, off, 64);
    }
    __shared__ float p1[4], p2[4];
    const int wave = t >> 6;
    if ((t & 63) == 0) { p1[wave] = s1; p2[wave] = s2; }
    __syncthreads();
    s1 = p1[0] + p1[1] + p1[2] + p1[3];
    s2 = p2[0] + p2[1] + p2[2] + p2[3];
    const float mean = s1 * (1.0f / D_);
    const float var  = s2 * (1.0f / D_) - mean * mean;
    const float rstd = rsqrtf(var + LN_EPS_);
    #pragma unroll
    for (int i = 0; i < 4; ++i) {
        int col = t + i * 256;
        float v = (vals[i] - mean) * rstd * g[col] + be[col];
        ushort h = f2bf_rne(v);
        oh[(size_t)row * D_ + col] = h;
        ol[(size_t)row * D_ + col] = f2bf_rne(v - bf2f(h));
    }
}

// ---------------------------------------------------------------------------
// Final LN: residual from planes. vv = a0 + a1 + (rh + rl); write fp32.
// out may alias a1 (each thread reads its own elements before writing).
// ---------------------------------------------------------------------------
__global__ __launch_bounds__(256) void add_ln_pr(const float* __restrict__ a0,
        const float* __restrict__ a1,
        const ushort* __restrict__ rh, const ushort* __restrict__ rl,
        const float* __restrict__ g, const float* __restrict__ be,
        float* __restrict__ out)
{
    const int row = blockIdx.x;
    const int t = threadIdx.x;
    float vals[4];
    float s1 = 0.0f, s2 = 0.0f;
    #pragma unroll
    for (int i = 0; i < 4; ++i) {
        int col = t + i * 256;
        size_t o = (size_t)row * D_ + col;
        float rr = bf2f(rh[o]) + bf2f(rl[o]);
        float vv = a0[o] + a1[o] + rr;
        vals[i] = vv;
        s1 += vv;
        s2 += vv * vv;
    }
    #pragma unroll
    for (int off = 32; off > 0; off >>= 1) {
        s1 += __shfl_down(s1, off, 64);
        s2 += __shfl_down(s2, off, 64);
    }
    __shared__ float p1[4], p2[4];
    const int wave = t >> 6;
    if ((t & 63) == 0) { p1[wave] = s1; p2[wave] = s2; }
    __syncthreads();
    s1 = p1[0] + p1[1] + p1[2] + p1[3];
    s2 = p2[0] + p2[1] + p2[2] + p2[3];
    const float mean = s1 * (1.0f / D_);
    const float var  = s2 * (1.0f / D_) - mean * mean;
    const float rstd = rsqrtf(var + LN_EPS_);
    #pragma unroll
    for (int i = 0; i < 4; ++i) {
        int col = t + i * 256;
        out[(size_t)row * D_ + col] = (vals[i] - mean) * rstd * g[col] + be[col];
    }
}

// ---------------------------------------------------------------------------
extern "C" void kernel_launch(void* const* d_in, const int* in_sizes, int n_in,
                              void* d_out, int out_size, void* d_ws, size_t ws_size,
                              hipStream_t stream)
{
    const float* Q   = (const float*)d_in[0];
    const float* K   = (const float*)d_in[1];
    const float* Wq  = (const float*)d_in[2];
    const float* bq  = (const float*)d_in[3];
    const float* Wk  = (const float*)d_in[4];
    const float* bk  = (const float*)d_in[5];
    const float* Wv  = (const float*)d_in[6];
    const float* bv  = (const float*)d_in[7];
    const float* Wo  = (const float*)d_in[8];
    const float* bo  = (const float*)d_in[9];
    const float* W1  = (const float*)d_in[10];
    const float* b1  = (const float*)d_in[11];
    const float* W2  = (const float*)d_in[12];
    const float* b2  = (const float*)d_in[13];
    const float* g0  = (const float*)d_in[14];
    const float* be0 = (const float*)d_in[15];
    const float* g1  = (const float*)d_in[16];
    const float* be1 = (const float*)d_in[17];

    unsigned char* Wb = (unsigned char*)d_ws;
    const size_t MBy = 1ull << 20;

    ushort* Qh   = (ushort*)(Wb +  0 * MBy);
    ushort* Ql   = (ushort*)(Wb +  8 * MBy);
    ushort* Kh   = (ushort*)(Wb + 16 * MBy);
    ushort* Kl   = (ushort*)(Wb + 24 * MBy);
    ushort* Wqh  = (ushort*)(Wb + 32 * MBy);
    ushort* Wql  = (ushort*)(Wb + 34 * MBy);
    ushort* Wkh  = (ushort*)(Wb + 36 * MBy);
    ushort* Wkl  = (ushort*)(Wb + 38 * MBy);
    ushort* Wvh  = (ushort*)(Wb + 40 * MBy);
    ushort* Wvl  = (ushort*)(Wb + 42 * MBy);
    ushort* Woh  = (ushort*)(Wb + 44 * MBy);
    ushort* Wol  = (ushort*)(Wb + 46 * MBy);
    ushort* qhp  = (ushort*)(Wb + 48 * MBy);
    ushort* khp  = (ushort*)(Wb + 56 * MBy);
    ushort* vhp  = (ushort*)(Wb + 64 * MBy);
    ushort* aOh  = (ushort*)(Wb + 72 * MBy);
    ushort* aOl  = (ushort*)(Wb + 80 * MBy);

    float*  oprj0 = (float*)(Wb + 16 * MBy);
    float*  oprj1 = (float*)(Wb + 56 * MBy);
    ushort* Xh    = (ushort*)(Wb + 32 * MBy);   // live to final LN
    ushort* Xl    = (ushort*)(Wb + 40 * MBy);
    ushort* W1h   = (ushort*)(Wb + 16 * MBy);
    ushort* W1l   = (ushort*)(Wb + 24 * MBy);
    ushort* Hih   = (ushort*)(Wb + 80 * MBy);   // 32MB: 80-112
    ushort* Hil   = (ushort*)(Wb + 48 * MBy);   // 32MB: 48-80
    ushort* W2h   = (ushort*)(Wb + 16 * MBy);
    ushort* W2l   = (ushort*)(Wb + 24 * MBy);
    float*  Y0    = (float*)(Wb +  0 * MBy);    // freed (ex-Qh/Ql region)
    float*  Y1    = (float*)d_out;              // scratch until final LN

    const int M = B_ * NQ_;
    const int n4act = M * D_ / 4;
    dim3 blk(256);
    dim3 gQKV(D_ / 128, M / 128, 3);
    dim3 gSK(D_ / 128, M / 128, 2);

    Rows2 r2;
    r2.src[0] = Q; r2.hi[0] = Qh; r2.lo[0] = Ql;
    r2.src[1] = K; r2.hi[1] = Kh; r2.lo[1] = Kl;
    split_rows2<<<dim3(n4act / 256, 1, 2), blk, 0, stream>>>(r2, n4act);

    Tr4 t4;
    t4.w[0] = Wq; t4.th[0] = Wqh; t4.tl[0] = Wql;
    t4.w[1] = Wk; t4.th[1] = Wkh; t4.tl[1] = Wkl;
    t4.w[2] = Wv; t4.th[2] = Wvh; t4.tl[2] = Wvl;
    t4.w[3] = Wo; t4.th[3] = Woh; t4.tl[3] = Wol;
    split_tr4<<<dim3(D_/32, D_/32, 4), blk, 0, stream>>>(t4);

    QkvArgs qa;
    qa.Ah[0] = Qh;  qa.Al[0] = Ql;  qa.Bh[0] = Wqh; qa.Bl[0] = Wql; qa.bias[0] = bq; qa.Co[0] = qhp;
    qa.Ah[1] = Kh;  qa.Al[1] = Kl;  qa.Bh[1] = Wkh; qa.Bl[1] = Wkl; qa.bias[1] = bk; qa.Co[1] = khp;
    qa.Ah[2] = Kh;  qa.Al[2] = Kl;  qa.Bh[2] = Wvh; qa.Bl[2] = Wvl; qa.bias[2] = bv; qa.Co[2] = vhp;
    gemm_qkv<<<gQKV, blk, 0, stream>>>(qa, M, D_, D_);

    flash_attn_mfma<<<dim3(1024), blk, 0, stream>>>(qhp, khp, vhp, aOh, aOl);

    // output projection, split-K=2 (2 blocks/CU) + LN0 -> planes only
    gemm_splitk2<<<gSK, blk, 0, stream>>>(aOh, aOl, Woh, Wol, bo, oprj0, oprj1, M, D_, D_);
    add_ln_so<<<M, blk, 0, stream>>>(oprj0, oprj1, Q, g0, be0, Xh, Xl);

    split_tr<<<dim3(DFF_/32, D_/32), blk, 0, stream>>>(W1, W1h, W1l, D_, DFF_);
    gemm_ffn1_256<<<dim3(DFF_/256, M/256), dim3(512), 0, stream>>>(
        Xh, Xl, W1h, W1l, b1, Hih, Hil, M, DFF_, D_);
    split_tr<<<dim3(D_/32, DFF_/32), blk, 0, stream>>>(W2, W2h, W2l, DFF_, D_);

    // FFN2: split-K=2 (r13 config); Y0 in freed region, Y1 = d_out
    gemm_splitk2<<<gSK, blk, 0, stream>>>(Hih, Hil, W2h, W2l, b2, Y0, Y1, M, D_, DFF_);
    add_ln_pr<<<M, blk, 0, stream>>>(Y0, Y1, Xh, Xl, g1, be1, (float*)d_out);
}